// Round 13
// baseline (59.452 us; speedup 1.0000x reference)
//
#include <hip/hip_runtime.h>

#define SEQ 8192
#define EMB 1024
#define DIM 64

typedef __attribute__((ext_vector_type(8))) short bf16x8;
typedef __attribute__((ext_vector_type(4))) float f32x4;
typedef __attribute__((ext_vector_type(16))) float f32x16;

#if __has_builtin(__builtin_amdgcn_exp2f)
#define EXP2 __builtin_amdgcn_exp2f
#else
#define EXP2 exp2f
#endif

// softmax scale folded with log2(e): (1/sqrt(8192)) * 1.4426950408889634
#define SCL 0.0159396779f

__device__ inline unsigned short f2bf(float f) {
    union { float f; unsigned u; } x; x.f = f;
    unsigned r = x.u + 0x7FFFu + ((x.u >> 16) & 1u);
    return (unsigned short)(r >> 16);
}

__device__ inline unsigned cvtpk(float lo, float hi) {
    unsigned r;
    asm("v_cvt_pk_bf16_f32 %0, %1, %2" : "=v"(r) : "v"(lo), "v"(hi));
    return r;
}

__device__ __forceinline__ void gload16(const float* g, float* l) {
    __builtin_amdgcn_global_load_lds(
        (const __attribute__((address_space(1))) unsigned*)g,
        (__attribute__((address_space(3))) unsigned*)l, 16, 0, 0);
}

// ---------------------------------------------------------------------------
// ws layout (bytes):
//  qkv @ 0        : q[8192][64] row-major | KF fragment | VF fragment  bf16
//  WF  @ 3145728  : [3][32 sg][4 wc][64 lane][8] bf16 fragment layout (393,216)
//  Opart @ 3538944 : [1120][32][64] f32 (9,175,040)
//  MLpart @ 12713984 : [1120][32][2] f32 (286,720)
// ---------------------------------------------------------------------------

// ---- W -> bf16 fragment layout, COALESCED (LDS transpose) ------------------
__global__ __launch_bounds__(256) void wt_kernel(
    const float* __restrict__ Wq, const float* __restrict__ Wk,
    const float* __restrict__ Wv, unsigned short* __restrict__ Wt)
{
    __shared__ float L[64][65];

    const int b   = (int)blockIdx.x;   // 0..47
    const int mat = b >> 4;
    const int kt  = b & 15;
    const float* W = (mat == 0) ? Wq : (mat == 1) ? Wk : Wv;
    const int tid = (int)threadIdx.x;

    const float* src = W + (size_t)kt * 64 * DIM;   // 64 rows x 64 cols
    #pragma unroll
    for (int i = 0; i < 16; ++i) {
        const int idx = i * 256 + tid;
        L[idx >> 6][idx & 63] = src[idx];
    }
    __syncthreads();

    unsigned short* dst = Wt + (size_t)(mat * 32 + kt * 2) * 2048;
    #pragma unroll
    for (int h = 0; h < 2; ++h) {
        const int s = tid * 16 + h * 8;          // short index, mult of 8
        const int sgo   = s >> 11;               // 0..1
        const int wcg   = (s >> 9) & 3;
        const int lanep = (s >> 3) & 63;
        const int qq = lanep >> 4, c = lanep & 15;
        const int kb = sgo * 32 + qq * 8;
        const int n  = wcg * 16 + c;
        uint4 w4;
        w4.x = cvtpk(L[kb + 0][n], L[kb + 1][n]);
        w4.y = cvtpk(L[kb + 2][n], L[kb + 3][n]);
        w4.z = cvtpk(L[kb + 4][n], L[kb + 5][n]);
        w4.w = cvtpk(L[kb + 6][n], L[kb + 7][n]);
        *(uint4*)&dst[s] = w4;
    }
}

__device__ inline bf16x8 cvt8(float4 a, float4 b) {
    union { unsigned u[4]; bf16x8 v; } r;
    r.u[0] = cvtpk(a.x, a.y);
    r.u[1] = cvtpk(a.z, a.w);
    r.u[2] = cvtpk(b.x, b.y);
    r.u[3] = cvtpk(b.z, b.w);
    return r.v;
}

// ---- Projection: counted-vmcnt pipeline, DEPTH-3, W 3-slot reg pipeline ----
// 768 blocks x 512 thr. Block = 32 rows x 64 cols; BK=128, 8 K-tiles,
// 4 LDS buffers (64 KB -> 2 blocks/CU), depth-3 prefetch.
// Window t = {STAGE(t):2, WLOAD(t):4} = 6 loads, issued in window order.
// At iter t: wait vmcnt(12) (t<=5) retires window t, keeping t+1,t+2 in
// flight; t=6 -> vmcnt(6); t=7 -> vmcnt(0).
__global__ __launch_bounds__(512) void proj_kernel(
    const float* __restrict__ x, const float* __restrict__ y, const float* __restrict__ z,
    const float* __restrict__ bq, const float* __restrict__ bk, const float* __restrict__ bv,
    const unsigned short* __restrict__ Wt, unsigned short* __restrict__ qkv)
{
    __shared__ float tile[4][32][128];   // 64 KB

    const int bid = (int)blockIdx.x;
    const int mat = bid >> 8;                 // 0=q,1=k,2=v (256 blocks each)
    const int rb  = (bid & 255) * 32;

    const int tid  = (int)threadIdx.x;
    const int lane = tid & 63;
    const int w    = tid >> 6;                // 0..7
    const int wr   = w >> 2;                  // row-tile 0..1
    const int wc   = w & 3;                   // col-tile 0..3
    const int c    = lane & 15;
    const int qq   = lane >> 4;

    const float* X  = (mat == 0) ? x  : (mat == 1) ? y  : z;
    const float* Bv = (mat == 0) ? bq : (mat == 1) ? bk : bv;
    const unsigned short* Wm = Wt + (size_t)mat * 65536;
    unsigned short* outp = qkv + (size_t)mat * (SEQ * DIM);

    f32x4 acc = (f32x4){0.f, 0.f, 0.f, 0.f};

    const int arow = wr * 16 + c;             // A-fragment LDS row
    const int swl  = arow & 7;                // read-side XOR (16B-chunk units)
    const unsigned short* Wp = Wm + (size_t)wc * 512 + (size_t)lane * 8;
    const bool swapped = (mat == 1);

    bf16x8 wreg[3][4];                        // W fragments, 3-deep (t%3, static)

    const int sr0 = w * 4 + (lane >> 5);
    #define STAGE(nb, t)                                                        \
        {                                                                       \
            const int k0_ = (t) * 128;                                          \
            _Pragma("unroll")                                                   \
            for (int j = 0; j < 2; ++j) {                                       \
                const int r_ = sr0 + j * 2;                                     \
                const float* src_ = X + (size_t)(rb + r_) * EMB + k0_           \
                                      + (((lane & 31) ^ (r_ & 7)) << 2);        \
                gload16(src_, &tile[nb][w * 4 + j * 2][0]);                     \
            }                                                                   \
        }

    #define WLOAD(slot, t)                                                      \
        {                                                                       \
            _Pragma("unroll")                                                   \
            for (int s = 0; s < 4; ++s)                                         \
                wreg[slot][s] = *(const bf16x8*)(Wp + (size_t)((t) * 4 + s) * 2048); \
        }

    #define COMP(bt, t)                                                         \
        {                                                                       \
            const float* rowp = &tile[bt][arow][0];                             \
            _Pragma("unroll")                                                   \
            for (int s = 0; s < 4; ++s) {                                       \
                float4 fa = *(const float4*)(rowp + s * 32                      \
                                             + (((qq * 2)     ^ swl) << 2));    \
                float4 fb = *(const float4*)(rowp + s * 32                      \
                                             + (((qq * 2 + 1) ^ swl) << 2));    \
                bf16x8 af = cvt8(fa, fb);                                       \
                bf16x8 bfr = wreg[(t) % 3][s];                                  \
                if (swapped)                                                    \
                    acc = __builtin_amdgcn_mfma_f32_16x16x32_bf16(bfr, af, acc, 0, 0, 0); \
                else                                                            \
                    acc = __builtin_amdgcn_mfma_f32_16x16x32_bf16(af, bfr, acc, 0, 0, 0); \
            }                                                                   \
        }

    // prologue: windows 0,1,2 (order pinned by memory clobbers)
    STAGE(0, 0);
    WLOAD(0, 0);
    asm volatile("" ::: "memory");
    STAGE(1, 1);
    WLOAD(1, 1);
    asm volatile("" ::: "memory");
    STAGE(2, 2);
    WLOAD(2, 2);

    #pragma unroll
    for (int t = 0; t < 8; ++t) {
        // retire window t; keep windows t+1,t+2 (12 loads) in flight
        if (t <= 5)      asm volatile("s_waitcnt vmcnt(12)" ::: "memory");
        else if (t == 6) asm volatile("s_waitcnt vmcnt(6)"  ::: "memory");
        else             asm volatile("s_waitcnt vmcnt(0)"  ::: "memory");
        __builtin_amdgcn_s_barrier();           // all waves' tile-t data landed
        if (t < 5) STAGE((t + 3) & 3, t + 3);   // buf (t-1)%4: read-done at barrier
        COMP(t & 3, t);
        if (t < 5) WLOAD((t + 3) % 3, t + 3);   // slot t%3 free after COMP(t)
    }
    #undef STAGE
    #undef WLOAD
    #undef COMP

    const int T = rb >> 5;
    if (mat == 0) {
        const int col = wc * 16 + c;
        const float bb = Bv[col];
        #pragma unroll
        for (int i = 0; i < 4; ++i) {
            const int row = rb + wr * 16 + qq * 4 + i;
            outp[(size_t)row * DIM + col] = f2bf(acc[i] + bb);
        }
    } else if (mat == 1) {   // KF: thread holds K^T (d = wc*16+qq*4+ii, kv = rb+wr*16+c)
        f32x4 bb4 = *(const f32x4*)&Bv[wc * 16 + qq * 4];
        const int base = (((T * 4 + wc) * 2 + (qq >> 1)) * 32 + wr * 16 + c) * 8 + (qq & 1) * 4;
        uint2 pk;
        pk.x = cvtpk(acc[0] + bb4[0], acc[1] + bb4[1]);
        pk.y = cvtpk(acc[2] + bb4[2], acc[3] + bb4[3]);
        *(uint2*)&outp[base] = pk;
    } else {                 // VF: thread holds V (kv = rb+wr*16+qq*4+ii, d = wc*16+c)
        const float bb = Bv[wc * 16 + c];
        const int base = ((((T * 2 + wr) * 2 + (wc >> 1)) * 2 + (qq >> 1)) * 32
                          + (wc & 1) * 16 + c) * 8 + (qq & 1) * 4;
        uint2 pk;
        pk.x = cvtpk(acc[0] + bb, acc[1] + bb);
        pk.y = cvtpk(acc[2] + bb, acc[3] + bb);
        *(uint2*)&outp[base] = pk;
    }
}

// ---- Flash attention: swapped-operand 32x32, KVBLK=64 pairs, defer-max -----
// 1152 blocks x 256 thr (4 waves). Unit = (qtile, 32-tile KV chunk).
// Software-pipelined: next pair's K prefetched after current QK; V loads
// after QK (wait hides under softmax). launch_bounds (256,3): DO NOT raise
// to 4 (R8: VGPR cap -> spill, FETCH 9.5->68 MB).
__global__ __launch_bounds__(256, 3) void attn_kernel(
    const unsigned short* __restrict__ qkv, float* __restrict__ out,
    float* __restrict__ Opart, float* __restrict__ MLpart)
{
    const unsigned short* Q  = qkv;
    const unsigned short* KF = qkv + SEQ * DIM;
    const unsigned short* VF = qkv + 2 * SEQ * DIM;

    __shared__ float Oall[4][32][68];
    __shared__ float Ml[4][32][2];
    __shared__ float sScl[4][32];
    __shared__ float sM[32];
    __shared__ float sL[32];

    // unit id, longest-first
    const int u = 1151 - (int)blockIdx.x;
    int g;
    if (u < 32) g = 0; else if (u < 96) g = 1; else if (u < 192) g = 2;
    else if (u < 320) g = 3; else if (u < 480) g = 4; else if (u < 672) g = 5;
    else if (u < 896) g = 6; else g = 7;
    const int o_  = u - 16 * g * (g + 1);
    const int qt  = 32 * g + o_ / (g + 1);
    const int cid = o_ - (o_ / (g + 1)) * (g + 1);

    const int m0 = qt * 32;
    const int tid = (int)threadIdx.x;
    const int lane = tid & 63;
    const int w = tid >> 6;        // 0..3
    const int col = lane & 31;     // q row within tile
    const int hi = lane >> 5;

    bf16x8 qf[4];
    {
        const unsigned short* Qr = Q + (size_t)(m0 + col) * DIM + hi * 8;
        #pragma unroll
        for (int ks = 0; ks < 4; ++ks) qf[ks] = *(const bf16x8*)(Qr + ks * 16);
    }

    f32x16 o0, o1;
    #pragma unroll
    for (int r = 0; r < 16; ++r) { o0[r] = 0.f; o1[r] = 0.f; }
    float m_i = -1e30f, l_i = 0.f;

    const int nT = qt + 1;
    const int tb = cid * 32;
    const int te = (tb + 32 < nT) ? (tb + 32) : nT;
    const int nC = te - tb;
    const int w0 = tb + ((nC * w) >> 2);
    const int w1 = tb + ((nC * (w + 1)) >> 2);
    const int nW = w1 - w0;
    const int nP = nW >> 1;

    // ---- K prefetch for the first pair ----
    bf16x8 kA[4], kB[4];
    if (nP > 0) {
        const unsigned short* kb0 = KF + (size_t)w0 * 2048 + (size_t)lane * 8;
        #pragma unroll
        for (int ks = 0; ks < 4; ++ks) kA[ks] = *(const bf16x8*)(kb0 + ks * 512);
        #pragma unroll
        for (int ks = 0; ks < 4; ++ks) kB[ks] = *(const bf16x8*)(kb0 + 2048 + ks * 512);
    }

    for (int pi = 0; pi < nP; ++pi) {
        const int t = w0 + 2 * pi;

        // ---- dual QK chains (consume kA/kB) ----
        f32x16 sa, sb;
        #pragma unroll
        for (int r = 0; r < 16; ++r) { sa[r] = 0.f; sb[r] = 0.f; }
        __builtin_amdgcn_s_setprio(1);
        #pragma unroll
        for (int ks = 0; ks < 4; ++ks) {
            sa = __builtin_amdgcn_mfma_f32_32x32x16_bf16(kA[ks], qf[ks], sa, 0, 0, 0);
            sb = __builtin_amdgcn_mfma_f32_32x32x16_bf16(kB[ks], qf[ks], sb, 0, 0, 0);
        }
        __builtin_amdgcn_s_setprio(0);

        // ---- prefetch next pair's K (regs dead after QK) ----
        if (pi + 1 < nP) {
            const unsigned short* kbn = KF + (size_t)(t + 2) * 2048 + (size_t)lane * 8;
            #pragma unroll
            for (int ks = 0; ks < 4; ++ks) kA[ks] = *(const bf16x8*)(kbn + ks * 512);
            #pragma unroll
            for (int ks = 0; ks < 4; ++ks) kB[ks] = *(const bf16x8*)(kbn + 2048 + ks * 512);
        }

        // ---- V loads issued here; wait falls before PV (under softmax) ----
        const unsigned short* vb_ = VF + (size_t)t * 2048 + (size_t)lane * 8;
        bf16x8 va[4], vbf[4];
        #pragma unroll
        for (int i = 0; i < 4; ++i) va[i]  = *(const bf16x8*)(vb_ + i * 1024);
        #pragma unroll
        for (int i = 0; i < 4; ++i) vbf[i] = *(const bf16x8*)(vb_ + 512 + i * 1024);

        float p0[16], p1[16];
        #pragma unroll
        for (int r = 0; r < 16; ++r) { p0[r] = sa[r] * SCL; p1[r] = sb[r] * SCL; }
        if (t + 1 == qt) {   // diagonal can only be the second tile of a pair
            #pragma unroll
            for (int r = 0; r < 16; ++r) {
                const int kvr = (r & 3) + 8 * (r >> 2) + 4 * hi;
                if (kvr > col) p1[r] = -1e30f;
            }
        }
        float tm = fmaxf(p0[0], p1[0]);
        #pragma unroll
        for (int r = 1; r < 16; ++r) tm = fmaxf(tm, fmaxf(p0[r], p1[r]));
        tm = fmaxf(tm, __shfl_xor(tm, 32));
        if (!__all(tm <= m_i + 2.0f)) {
            const float mn = fmaxf(m_i, tm);
            const float alpha = EXP2(m_i - mn);
            m_i = mn;
            l_i *= alpha;
            #pragma unroll
            for (int r = 0; r < 16; ++r) { o0[r] *= alpha; o1[r] *= alpha; }
        }
        float rs = 0.f;
        #pragma unroll
        for (int r = 0; r < 16; ++r) { p0[r] = EXP2(p0[r] - m_i); rs += p0[r]; }
        #pragma unroll
        for (int r = 0; r < 16; ++r) { p1[r] = EXP2(p1[r] - m_i); rs += p1[r]; }
        rs += __shfl_xor(rs, 32);
        l_i += rs;

        unsigned pwA[8], pwB[8];
        #pragma unroll
        for (int i = 0; i < 8; ++i) pwA[i] = cvtpk(p0[2 * i], p0[2 * i + 1]);
        #pragma unroll
        for (int i = 0; i < 8; ++i) pwB[i] = cvtpk(p1[2 * i], p1[2 * i + 1]);
        asm volatile("v_permlane32_swap_b32 %0, %1" : "+v"(pwA[0]), "+v"(pwA[2]));
        asm volatile("v_permlane32_swap_b32 %0, %1" : "+v"(pwA[1]), "+v"(pwA[3]));
        asm volatile("v_permlane32_swap_b32 %0, %1" : "+v"(pwA[4]), "+v"(pwA[6]));
        asm volatile("v_permlane32_swap_b32 %0, %1" : "+v"(pwA[5]), "+v"(pwA[7]));
        asm volatile("v_permlane32_swap_b32 %0, %1" : "+v"(pwB[0]), "+v"(pwB[2]));
        asm volatile("v_permlane32_swap_b32 %0, %1" : "+v"(pwB[1]), "+v"(pwB[3]));
        asm volatile("v_permlane32_swap_b32 %0, %1" : "+v"(pwB[4]), "+v"(pwB[6]));
        asm volatile("v_permlane32_swap_b32 %0, %1" : "+v"(pwB[5]), "+v"(pwB[7]));
        union { unsigned uu[4]; bf16x8 v; } pa0, pa1, pb0, pb1;
        pa0.uu[0] = pwA[0]; pa0.uu[1] = pwA[1]; pa0.uu[2] = pwA[2]; pa0.uu[3] = pwA[3];
        pa1.uu[0] = pwA[4]; pa1.uu[1] = pwA[5]; pa1.uu[2] = pwA[6]; pa1.uu[3] = pwA[7];
        pb0.uu[0] = pwB[0]; pb0.uu[1] = pwB[1]; pb0.uu[2] = pwB[2]; pb0.uu[3] = pwB[3];
        pb1.uu[0] = pwB[4]; pb1.uu[1] = pwB[5]; pb1.uu[2] = pwB[6]; pb1.uu[3] = pwB[7];

        __builtin_amdgcn_s_setprio(1);
        o0 = __builtin_amdgcn_mfma_f32_32x32x16_bf16(va[0],  pa0.v, o0, 0, 0, 0);
        o1 = __builtin_amdgcn_mfma_f32_32x32x16_bf16(vbf[0], pa0.v, o1, 0, 0, 0);
        o0 = __builtin_amdgcn_mfma_f32_32x32x16_bf16(va[1],  pa1.v, o0, 0, 0, 0);
        o1 = __builtin_amdgcn_mfma_f32_32x32x16_bf16(vbf[1], pa1.v, o1, 0, 0, 0);
        o0 = __builtin_amdgcn_mfma_f32_32x32x16_bf16(va[2],  pb0.v, o0, 0, 0, 0);
        o1 = __builtin_amdgcn_mfma_f32_32x32x16_bf16(vbf[2], pb0.v, o1, 0, 0, 0);
        o0 = __builtin_amdgcn_mfma_f32_32x32x16_bf16(va[3],  pb1.v, o0, 0, 0, 0);
        o1 = __builtin_amdgcn_mfma_f32_32x32x16_bf16(vbf[3], pb1.v, o1, 0, 0, 0);
        __builtin_amdgcn_s_setprio(0);
    }

    if (nW & 1) {   // tail single tile
        const int t = w1 - 1;
        const unsigned short* kb = KF + (size_t)t * 2048 + (size_t)lane * 8;
        const unsigned short* vb_ = VF + (size_t)t * 2048 + (size_t)lane * 8;
        bf16x8 kT[4];
        #pragma unroll
        for (int ks = 0; ks < 4; ++ks) kT[ks] = *(const bf16x8*)(kb + ks * 512);
        bf16x8 va0 = *(const bf16x8*)(vb_);
        bf16x8 va1 = *(const bf16x8*)(vb_ + 1024);
        bf16x8 vb0 = *(const bf16x8*)(vb_ + 512);
        bf16x8 vb1 = *(const bf16x8*)(vb_ + 1536);

        f32x16 sa;
        #pragma unroll
        for (int r = 0; r < 16; ++r) sa[r] = 0.f;
        __builtin_amdgcn_s_setprio(1);
        #pragma unroll
        for (int ks = 0; ks < 4; ++ks)
            sa = __builtin_amdgcn_mfma_f32_32x32x16_bf16(kT[ks], qf[ks], sa, 0, 0, 0);
        __builtin_amdgcn_s_setprio(0);

        float p0[16];
        #pragma unroll
        for (int r = 0; r < 16; ++r) p0[r] = sa[r] * SCL;
        if (t == qt) {
            #pragma unroll
            for (int r = 0; r < 16; ++r) {
                const int kvr = (r & 3) + 8 * (r >> 2) + 4 * hi;
                if (kvr > col) p0[r] = -1e30f;
            }
        }
        float tm = p0[0];
        #pragma unroll
        for (int r = 1; r < 16; ++r) tm = fmaxf(tm, p0[r]);
        tm = fmaxf(tm, __shfl_xor(tm, 32));
        if (!__all(tm <= m_i + 2.0f)) {
            const float mn = fmaxf(m_i, tm);
            const float alpha = EXP2(m_i - mn);
            m_i = mn;
            l_i *= alpha;
            #pragma unroll
            for (int r = 0; r < 16; ++r) { o0[r] *= alpha; o1[r] *= alpha; }
        }
        float rs = 0.f;
        #pragma unroll
        for (int r = 0; r < 16; ++r) { p0[r] = EXP2(p0[r] - m_i); rs += p0[r]; }
        rs += __shfl_xor(rs, 32);
        l_i += rs;

        unsigned pwA[8];
        #pragma unroll
        for (int i = 0; i < 8; ++i) pwA[i] = cvtpk(p0[2 * i], p0[2 * i + 1]);
        asm volatile("v_permlane32_swap_b32 %0, %1" : "+v"(pwA[0]), "+v"(pwA[2]));
        asm volatile("v_permlane32_swap_b32 %0, %1" : "+v"(pwA[1]), "+v"(pwA[3]));
        asm volatile("v_permlane32_swap_b32 %0, %1" : "+v"(pwA[4]), "+v"(pwA[6]));
        asm volatile("v_permlane32_swap_b32 %0, %1" : "+v"(pwA[5]), "+v"(pwA[7]));
        union { unsigned uu[4]; bf16x8 v; } pa0, pa1;
        pa0.uu[0] = pwA[0]; pa0.uu[1] = pwA[1]; pa0.uu[2] = pwA[2]; pa0.uu[3] = pwA[3];
        pa1.uu[0] = pwA[4]; pa1.uu[1] = pwA[5]; pa1.uu[2] = pwA[6]; pa1.uu[3] = pwA[7];

        __builtin_amdgcn_s_setprio(1);
        o0 = __builtin_amdgcn_mfma_f32_32x32x16_bf16(va0, pa0.v, o0, 0, 0, 0);
        o1 = __builtin_amdgcn_mfma_f32_32x32x16_bf16(vb0, pa0.v, o1, 0, 0, 0);
        o0 = __builtin_amdgcn_mfma_f32_32x32x16_bf16(va1, pa1.v, o0, 0, 0, 0);
        o1 = __builtin_amdgcn_mfma_f32_32x32x16_bf16(vb1, pa1.v, o1, 0, 0, 0);
        __builtin_amdgcn_s_setprio(0);
    }

    // per-wave partial -> LDS (O^T: lane col = q, regs = d)
    #pragma unroll
    for (int r = 0; r < 16; ++r) {
        const int d = (r & 3) + 8 * (r >> 2) + 4 * hi;
        Oall[w][col][d]      = o0[r];
        Oall[w][col][32 + d] = o1[r];
    }
    if (hi == 0) { Ml[w][col][0] = m_i; Ml[w][col][1] = l_i; }
    __syncthreads();

    // 2-barrier epilogue: tid<32 computes M, scl, L in one pass
    if (tid < 32) {
        float M = Ml[0][tid][0];
        #pragma unroll
        for (int w2 = 1; w2 < 4; ++w2) M = fmaxf(M, Ml[w2][tid][0]);
        float L = 0.f;
        #pragma unroll
        for (int w2 = 0; w2 < 4; ++w2) {
            const float sc = EXP2(Ml[w2][tid][0] - M);
            sScl[w2][tid] = sc;
            L += Ml[w2][tid][1] * sc;
        }
        sM[tid] = M;
        sL[tid] = L;
    }
    __syncthreads();

    const int r = tid >> 3;
    const int c0 = (tid & 7) * 8;
    f32x4 a0 = (f32x4){0.f, 0.f, 0.f, 0.f};
    f32x4 a1 = (f32x4){0.f, 0.f, 0.f, 0.f};
    #pragma unroll
    for (int w2 = 0; w2 < 4; ++w2) {
        const float sc = sScl[w2][r];
        const float* Orow = &Oall[w2][r][c0];
        a0 += (*(const f32x4*)(Orow)) * sc;
        a1 += (*(const f32x4*)(Orow + 4)) * sc;
    }
    if (qt < 32) {   // single chunk: final output
        const float inv = 1.f / sL[r];
        float* op = out + (size_t)(m0 + r) * DIM + c0;
        *(f32x4*)(op)     = a0 * inv;
        *(f32x4*)(op + 4) = a1 * inv;
    } else {         // partial for fixup
        const int pb = 16 * (g - 1) * (g + 2) + (qt - 32 * g) * (g + 1) + cid;
        float* op = Opart + (size_t)pb * 2048 + r * 64 + c0;
        *(f32x4*)(op)     = a0;
        *(f32x4*)(op + 4) = a1;
        if (tid < 32) {
            MLpart[(size_t)pb * 64 + tid * 2]     = sM[tid];
            MLpart[(size_t)pb * 64 + tid * 2 + 1] = sL[tid];
        }
    }
}

// ---- Fixup: merge chunk partials for qt >= 32. 224 blocks x 256 ------------
__global__ __launch_bounds__(256) void fixup_kernel(
    const float* __restrict__ Opart, const float* __restrict__ MLpart,
    float* __restrict__ out)
{
    __shared__ float sScl[8][32];
    __shared__ float sInvL[32];

    const int qt = 32 + (int)blockIdx.x;
    const int g  = qt >> 5;
    const int nc = g + 1;
    const int pb = 16 * (g - 1) * (g + 2) + (qt - 32 * g) * nc;
    const int tid = (int)threadIdx.x;

    if (tid < 32) {
        float M = -1e30f;
        for (int c2 = 0; c2 < nc; ++c2)
            M = fmaxf(M, MLpart[(size_t)(pb + c2) * 64 + tid * 2]);
        float L = 0.f;
        for (int c2 = 0; c2 < nc; ++c2) {
            const float sc = EXP2(MLpart[(size_t)(pb + c2) * 64 + tid * 2] - M);
            sScl[c2][tid] = sc;
            L += MLpart[(size_t)(pb + c2) * 64 + tid * 2 + 1] * sc;
        }
        sInvL[tid] = 1.f / L;
    }
    __syncthreads();

    const int r = tid >> 3;
    const int c0 = (tid & 7) * 8;
    f32x4 a0 = (f32x4){0.f, 0.f, 0.f, 0.f};
    f32x4 a1 = (f32x4){0.f, 0.f, 0.f, 0.f};
    for (int c2 = 0; c2 < nc; ++c2) {
        const float sc = sScl[c2][r];
        const float* Op = Opart + (size_t)(pb + c2) * 2048 + r * 64 + c0;
        a0 += (*(const f32x4*)(Op)) * sc;
        a1 += (*(const f32x4*)(Op + 4)) * sc;
    }
    const float inv = sInvL[r];
    float* op = out + (size_t)(qt * 32 + r) * DIM + c0;
    *(f32x4*)(op)     = a0 * inv;
    *(f32x4*)(op + 4) = a1 * inv;
}

extern "C" void kernel_launch(void* const* d_in, const int* in_sizes, int n_in,
                              void* d_out, int out_size, void* d_ws, size_t ws_size,
                              hipStream_t stream) {
    const float* x  = (const float*)d_in[0];
    const float* y  = (const float*)d_in[1];
    const float* z  = (const float*)d_in[2];
    const float* Wq = (const float*)d_in[3];
    const float* bq = (const float*)d_in[4];
    const float* Wk = (const float*)d_in[5];
    const float* bk = (const float*)d_in[6];
    const float* Wv = (const float*)d_in[7];
    const float* bv = (const float*)d_in[8];

    unsigned short* qkv = (unsigned short*)d_ws;
    unsigned short* Wt  = (unsigned short*)((char*)d_ws + 3145728);
    float* Opart        = (float*)((char*)d_ws + 3538944);
    float* MLpart       = (float*)((char*)d_ws + 12713984);
    float* out          = (float*)d_out;

    hipLaunchKernelGGL(wt_kernel,    dim3(48),   dim3(256), 0, stream, Wq, Wk, Wv, Wt);
    hipLaunchKernelGGL(proj_kernel,  dim3(768),  dim3(512), 0, stream, x, y, z, bq, bk, bv, Wt, qkv);
    hipLaunchKernelGGL(attn_kernel,  dim3(1152), dim3(256), 0, stream, qkv, out, Opart, MLpart);
    hipLaunchKernelGGL(fixup_kernel, dim3(224),  dim3(256), 0, stream, Opart, MLpart, out);
}

// Round 14
// 54.396 us; speedup vs baseline: 1.0929x; 1.0929x over previous
//
#include <hip/hip_runtime.h>

#define SEQ 8192
#define EMB 1024
#define DIM 64

typedef __attribute__((ext_vector_type(8))) short bf16x8;
typedef __attribute__((ext_vector_type(4))) float f32x4;
typedef __attribute__((ext_vector_type(16))) float f32x16;

#if __has_builtin(__builtin_amdgcn_exp2f)
#define EXP2 __builtin_amdgcn_exp2f
#else
#define EXP2 exp2f
#endif

// softmax scale folded with log2(e): (1/sqrt(8192)) * 1.4426950408889634
#define SCL 0.0159396779f

__device__ inline unsigned short f2bf(float f) {
    union { float f; unsigned u; } x; x.f = f;
    unsigned r = x.u + 0x7FFFu + ((x.u >> 16) & 1u);
    return (unsigned short)(r >> 16);
}

__device__ inline unsigned cvtpk(float lo, float hi) {
    unsigned r;
    asm("v_cvt_pk_bf16_f32 %0, %1, %2" : "=v"(r) : "v"(lo), "v"(hi));
    return r;
}

__device__ __forceinline__ void gload16(const float* g, float* l) {
    __builtin_amdgcn_global_load_lds(
        (const __attribute__((address_space(1))) unsigned*)g,
        (__attribute__((address_space(3))) unsigned*)l, 16, 0, 0);
}

// ---------------------------------------------------------------------------
// ws layout (bytes):
//  qkv @ 0        : q[8192][64] row-major | KF fragment | VF fragment  bf16
//  WF  @ 3145728  : [3][32 sg][4 wc][64 lane][8] bf16 fragment layout (393,216)
//  Opart @ 3538944 : [1120][32][64] f32 (9,175,040)
//  MLpart @ 12713984 : [1120][32][2] f32 (286,720)
// ---------------------------------------------------------------------------

// ---- W -> bf16 fragment layout, COALESCED (LDS transpose) ------------------
__global__ __launch_bounds__(256) void wt_kernel(
    const float* __restrict__ Wq, const float* __restrict__ Wk,
    const float* __restrict__ Wv, unsigned short* __restrict__ Wt)
{
    __shared__ float L[64][65];

    const int b   = (int)blockIdx.x;   // 0..47
    const int mat = b >> 4;
    const int kt  = b & 15;
    const float* W = (mat == 0) ? Wq : (mat == 1) ? Wk : Wv;
    const int tid = (int)threadIdx.x;

    const float* src = W + (size_t)kt * 64 * DIM;   // 64 rows x 64 cols
    #pragma unroll
    for (int i = 0; i < 16; ++i) {
        const int idx = i * 256 + tid;
        L[idx >> 6][idx & 63] = src[idx];
    }
    __syncthreads();

    unsigned short* dst = Wt + (size_t)(mat * 32 + kt * 2) * 2048;
    #pragma unroll
    for (int h = 0; h < 2; ++h) {
        const int s = tid * 16 + h * 8;          // short index, mult of 8
        const int sgo   = s >> 11;               // 0..1
        const int wcg   = (s >> 9) & 3;
        const int lanep = (s >> 3) & 63;
        const int qq = lanep >> 4, c = lanep & 15;
        const int kb = sgo * 32 + qq * 8;
        const int n  = wcg * 16 + c;
        uint4 w4;
        w4.x = cvtpk(L[kb + 0][n], L[kb + 1][n]);
        w4.y = cvtpk(L[kb + 2][n], L[kb + 3][n]);
        w4.z = cvtpk(L[kb + 4][n], L[kb + 5][n]);
        w4.w = cvtpk(L[kb + 6][n], L[kb + 7][n]);
        *(uint4*)&dst[s] = w4;
    }
}

__device__ inline bf16x8 cvt8(float4 a, float4 b) {
    union { unsigned u[4]; bf16x8 v; } r;
    r.u[0] = cvtpk(a.x, a.y);
    r.u[1] = cvtpk(a.z, a.w);
    r.u[2] = cvtpk(b.x, b.y);
    r.u[3] = cvtpk(b.z, b.w);
    return r.v;
}

// ---- Projection: BARRIER-FREE per-wave streaming ---------------------------
// 768 blocks x 256 thr (4 waves). Block = 32 rows x 64 cols, 2-way K-split.
// Wave (wr,kh) owns 16 rows x K-half(512), stages into WAVE-PRIVATE LDS
// (3 bufs x 4 KB/wave = 48 KB/block) -> no s_barrier in the main loop;
// sync is the wave's own counted vmcnt. Window t = {4 X-gload, 8 W-load}=12,
// depth-3: vmcnt(24) steady (windows t+1,t+2 stay in flight), 12 @ t=6, 0 @ 7.
// Buffer (t+3)%3 == t%3 reused right after COMP(t) (in-wave order, safe).
// Epilogue: 2 barriers total — combine K-halves in LDS, write q/KF/VF
// coalesced (uint4/thread).
__global__ __launch_bounds__(256) void proj_kernel(
    const float* __restrict__ x, const float* __restrict__ y, const float* __restrict__ z,
    const float* __restrict__ bq, const float* __restrict__ bk, const float* __restrict__ bv,
    const unsigned short* __restrict__ Wt, unsigned short* __restrict__ qkv)
{
    __shared__ float pool[12288];   // 48 KB: 4 waves x 3 bufs x 1024 f32

    const int bid = (int)blockIdx.x;
    const int mat = bid >> 8;                 // 0=q,1=k,2=v (256 blocks each)
    const int rb  = (bid & 255) * 32;

    const int tid  = (int)threadIdx.x;
    const int lane = tid & 63;
    const int w    = tid >> 6;                // 0..3
    const int wr   = w & 1;                   // row-half
    const int kh   = w >> 1;                  // k-half
    const int c    = lane & 15;
    const int qq   = lane >> 4;

    const float* X  = (mat == 0) ? x  : (mat == 1) ? y  : z;
    const float* Bv = (mat == 0) ? bq : (mat == 1) ? bk : bv;
    const unsigned short* Wm = Wt + (size_t)mat * 65536;
    unsigned short* outp = qkv + (size_t)mat * (SEQ * DIM);

    float* poolw = pool + w * 3072;
    const float* Xw = X + (size_t)(rb + wr * 16) * EMB + kh * 512;

    f32x4 acc[4];
    #pragma unroll
    for (int i = 0; i < 4; ++i) acc[i] = (f32x4){0.f, 0.f, 0.f, 0.f};

    bf16x8 wreg[3][8];

    // window t: 4 X-gloads (1 KB each, 4 rows x 256B, XOR-preswizzled source)
    //           + 8 W-frag loads (lane-contiguous dwordx4)
    #define STAGE(buf, t)                                                       \
        {                                                                       \
            const int k0_ = (t) * 64;                                           \
            _Pragma("unroll")                                                   \
            for (int j = 0; j < 4; ++j) {                                       \
                const int rloc = j * 4 + qq;                                    \
                const int g = c ^ (rloc & 7);                                   \
                gload16(Xw + (size_t)rloc * EMB + k0_ + g * 4,                  \
                        poolw + (buf) * 1024 + j * 256);                        \
            }                                                                   \
        }
    #define WLOAD(slot, t)                                                      \
        {                                                                       \
            const int sgb = kh * 16 + (t) * 2;                                  \
            _Pragma("unroll")                                                   \
            for (int ks2 = 0; ks2 < 2; ++ks2)                                   \
                _Pragma("unroll")                                               \
                for (int wc2 = 0; wc2 < 4; ++wc2)                               \
                    wreg[slot][ks2 * 4 + wc2] = *(const bf16x8*)(Wm +           \
                        ((size_t)((sgb + ks2) * 4 + wc2) * 64 + lane) * 8);     \
        }
    #define COMP(bt)                                                            \
        {                                                                       \
            const float* rowb = poolw + (bt) * 1024 + c * 64;                   \
            _Pragma("unroll")                                                   \
            for (int ks2 = 0; ks2 < 2; ++ks2) {                                 \
                float4 fa = *(const float4*)(rowb +                             \
                                (((ks2 * 8 + qq * 2)     ^ (c & 7)) << 2));     \
                float4 fb = *(const float4*)(rowb +                             \
                                (((ks2 * 8 + qq * 2 + 1) ^ (c & 7)) << 2));     \
                bf16x8 af = cvt8(fa, fb);                                       \
                _Pragma("unroll")                                               \
                for (int wc2 = 0; wc2 < 4; ++wc2)                               \
                    acc[wc2] = __builtin_amdgcn_mfma_f32_16x16x32_bf16(         \
                        af, wreg[bt][ks2 * 4 + wc2], acc[wc2], 0, 0, 0);        \
            }                                                                   \
        }

    // prologue: windows 0,1,2 (FIFO order pinned by memory clobbers)
    STAGE(0, 0); WLOAD(0, 0);
    asm volatile("" ::: "memory");
    STAGE(1, 1); WLOAD(1, 1);
    asm volatile("" ::: "memory");
    STAGE(2, 2); WLOAD(2, 2);

    #pragma unroll
    for (int t = 0; t < 8; ++t) {
        if (t <= 5)      asm volatile("s_waitcnt vmcnt(24)" ::: "memory");
        else if (t == 6) asm volatile("s_waitcnt vmcnt(12)" ::: "memory");
        else             asm volatile("s_waitcnt vmcnt(0)"  ::: "memory");
        COMP(t % 3);
        if (t < 5) { STAGE(t % 3, t + 3); WLOAD(t % 3, t + 3); }
    }
    #undef STAGE
    #undef WLOAD
    #undef COMP

    // ---- combine K-halves (reuse pool; all waves done first) ----
    __syncthreads();
    float (*part)[32][68] = (float (*)[32][68])pool;   // 2x32x68 = 4352 f32
    #pragma unroll
    for (int wc2 = 0; wc2 < 4; ++wc2)
        #pragma unroll
        for (int i = 0; i < 4; ++i)
            part[kh][wr * 16 + qq * 4 + i][wc2 * 16 + c] = acc[wc2][i];
    __syncthreads();

    const int T = rb >> 5;
    if (mat == 0) {                     // q row-major
        const int row = tid >> 3;
        const int c0  = (tid & 7) * 8;
        float v[8];
        #pragma unroll
        for (int j = 0; j < 8; ++j)
            v[j] = part[0][row][c0 + j] + part[1][row][c0 + j] + Bv[c0 + j];
        uint4 pk4;
        pk4.x = cvtpk(v[0], v[1]); pk4.y = cvtpk(v[2], v[3]);
        pk4.z = cvtpk(v[4], v[5]); pk4.w = cvtpk(v[6], v[7]);
        *(uint4*)&outp[(size_t)(rb + row) * DIM + c0] = pk4;
    } else if (mat == 1) {              // KF fragment tile T
        const int ks2 = tid >> 6;
        const int hi2 = (tid >> 5) & 1;
        const int col = tid & 31;
        const int d0  = ks2 * 16 + hi2 * 8;
        float v[8];
        #pragma unroll
        for (int j = 0; j < 8; ++j)
            v[j] = part[0][col][d0 + j] + part[1][col][d0 + j] + Bv[d0 + j];
        uint4 pk4;
        pk4.x = cvtpk(v[0], v[1]); pk4.y = cvtpk(v[2], v[3]);
        pk4.z = cvtpk(v[4], v[5]); pk4.w = cvtpk(v[6], v[7]);
        *(uint4*)&outp[(size_t)T * 2048 + tid * 8] = pk4;
    } else {                            // VF fragment tile T
        const int i2  = tid >> 7;
        const int h   = (tid >> 6) & 1;
        const int hi2 = (tid >> 5) & 1;
        const int col = tid & 31;
        const int r0  = i2 * 16 + hi2 * 8;
        const int cv  = h * 32 + col;
        const float bb = Bv[cv];
        float v[8];
        #pragma unroll
        for (int j = 0; j < 8; ++j)
            v[j] = part[0][r0 + j][cv] + part[1][r0 + j][cv] + bb;
        uint4 pk4;
        pk4.x = cvtpk(v[0], v[1]); pk4.y = cvtpk(v[2], v[3]);
        pk4.z = cvtpk(v[4], v[5]); pk4.w = cvtpk(v[6], v[7]);
        *(uint4*)&outp[(size_t)T * 2048 + tid * 8] = pk4;
    }
}

// ---- Flash attention: swapped-operand 32x32, KVBLK=64 pairs, defer-max -----
// 1152 blocks x 256 thr (4 waves). Unit = (qtile, 32-tile KV chunk).
// Software-pipelined: next pair's K prefetched after current QK; V loads
// after QK (wait hides under softmax). launch_bounds (256,3): DO NOT raise
// to 4 (R8: VGPR cap -> spill, FETCH 9.5->68 MB).
__global__ __launch_bounds__(256, 3) void attn_kernel(
    const unsigned short* __restrict__ qkv, float* __restrict__ out,
    float* __restrict__ Opart, float* __restrict__ MLpart)
{
    const unsigned short* Q  = qkv;
    const unsigned short* KF = qkv + SEQ * DIM;
    const unsigned short* VF = qkv + 2 * SEQ * DIM;

    __shared__ float Oall[4][32][68];
    __shared__ float Ml[4][32][2];
    __shared__ float sScl[4][32];
    __shared__ float sM[32];
    __shared__ float sL[32];

    // unit id, longest-first
    const int u = 1151 - (int)blockIdx.x;
    int g;
    if (u < 32) g = 0; else if (u < 96) g = 1; else if (u < 192) g = 2;
    else if (u < 320) g = 3; else if (u < 480) g = 4; else if (u < 672) g = 5;
    else if (u < 896) g = 6; else g = 7;
    const int o_  = u - 16 * g * (g + 1);
    const int qt  = 32 * g + o_ / (g + 1);
    const int cid = o_ - (o_ / (g + 1)) * (g + 1);

    const int m0 = qt * 32;
    const int tid = (int)threadIdx.x;
    const int lane = tid & 63;
    const int w = tid >> 6;        // 0..3
    const int col = lane & 31;     // q row within tile
    const int hi = lane >> 5;

    bf16x8 qf[4];
    {
        const unsigned short* Qr = Q + (size_t)(m0 + col) * DIM + hi * 8;
        #pragma unroll
        for (int ks = 0; ks < 4; ++ks) qf[ks] = *(const bf16x8*)(Qr + ks * 16);
    }

    f32x16 o0, o1;
    #pragma unroll
    for (int r = 0; r < 16; ++r) { o0[r] = 0.f; o1[r] = 0.f; }
    float m_i = -1e30f, l_i = 0.f;

    const int nT = qt + 1;
    const int tb = cid * 32;
    const int te = (tb + 32 < nT) ? (tb + 32) : nT;
    const int nC = te - tb;
    const int w0 = tb + ((nC * w) >> 2);
    const int w1 = tb + ((nC * (w + 1)) >> 2);
    const int nW = w1 - w0;
    const int nP = nW >> 1;

    // ---- K prefetch for the first pair ----
    bf16x8 kA[4], kB[4];
    if (nP > 0) {
        const unsigned short* kb0 = KF + (size_t)w0 * 2048 + (size_t)lane * 8;
        #pragma unroll
        for (int ks = 0; ks < 4; ++ks) kA[ks] = *(const bf16x8*)(kb0 + ks * 512);
        #pragma unroll
        for (int ks = 0; ks < 4; ++ks) kB[ks] = *(const bf16x8*)(kb0 + 2048 + ks * 512);
    }

    for (int pi = 0; pi < nP; ++pi) {
        const int t = w0 + 2 * pi;

        // ---- dual QK chains (consume kA/kB) ----
        f32x16 sa, sb;
        #pragma unroll
        for (int r = 0; r < 16; ++r) { sa[r] = 0.f; sb[r] = 0.f; }
        __builtin_amdgcn_s_setprio(1);
        #pragma unroll
        for (int ks = 0; ks < 4; ++ks) {
            sa = __builtin_amdgcn_mfma_f32_32x32x16_bf16(kA[ks], qf[ks], sa, 0, 0, 0);
            sb = __builtin_amdgcn_mfma_f32_32x32x16_bf16(kB[ks], qf[ks], sb, 0, 0, 0);
        }
        __builtin_amdgcn_s_setprio(0);

        // ---- prefetch next pair's K (regs dead after QK) ----
        if (pi + 1 < nP) {
            const unsigned short* kbn = KF + (size_t)(t + 2) * 2048 + (size_t)lane * 8;
            #pragma unroll
            for (int ks = 0; ks < 4; ++ks) kA[ks] = *(const bf16x8*)(kbn + ks * 512);
            #pragma unroll
            for (int ks = 0; ks < 4; ++ks) kB[ks] = *(const bf16x8*)(kbn + 2048 + ks * 512);
        }

        // ---- V loads issued here; wait falls before PV (under softmax) ----
        const unsigned short* vb_ = VF + (size_t)t * 2048 + (size_t)lane * 8;
        bf16x8 va[4], vbf[4];
        #pragma unroll
        for (int i = 0; i < 4; ++i) va[i]  = *(const bf16x8*)(vb_ + i * 1024);
        #pragma unroll
        for (int i = 0; i < 4; ++i) vbf[i] = *(const bf16x8*)(vb_ + 512 + i * 1024);

        float p0[16], p1[16];
        #pragma unroll
        for (int r = 0; r < 16; ++r) { p0[r] = sa[r] * SCL; p1[r] = sb[r] * SCL; }
        if (t + 1 == qt) {   // diagonal can only be the second tile of a pair
            #pragma unroll
            for (int r = 0; r < 16; ++r) {
                const int kvr = (r & 3) + 8 * (r >> 2) + 4 * hi;
                if (kvr > col) p1[r] = -1e30f;
            }
        }
        float tm = fmaxf(p0[0], p1[0]);
        #pragma unroll
        for (int r = 1; r < 16; ++r) tm = fmaxf(tm, fmaxf(p0[r], p1[r]));
        tm = fmaxf(tm, __shfl_xor(tm, 32));
        if (!__all(tm <= m_i + 2.0f)) {
            const float mn = fmaxf(m_i, tm);
            const float alpha = EXP2(m_i - mn);
            m_i = mn;
            l_i *= alpha;
            #pragma unroll
            for (int r = 0; r < 16; ++r) { o0[r] *= alpha; o1[r] *= alpha; }
        }
        float rs = 0.f;
        #pragma unroll
        for (int r = 0; r < 16; ++r) { p0[r] = EXP2(p0[r] - m_i); rs += p0[r]; }
        #pragma unroll
        for (int r = 0; r < 16; ++r) { p1[r] = EXP2(p1[r] - m_i); rs += p1[r]; }
        rs += __shfl_xor(rs, 32);
        l_i += rs;

        unsigned pwA[8], pwB[8];
        #pragma unroll
        for (int i = 0; i < 8; ++i) pwA[i] = cvtpk(p0[2 * i], p0[2 * i + 1]);
        #pragma unroll
        for (int i = 0; i < 8; ++i) pwB[i] = cvtpk(p1[2 * i], p1[2 * i + 1]);
        asm volatile("v_permlane32_swap_b32 %0, %1" : "+v"(pwA[0]), "+v"(pwA[2]));
        asm volatile("v_permlane32_swap_b32 %0, %1" : "+v"(pwA[1]), "+v"(pwA[3]));
        asm volatile("v_permlane32_swap_b32 %0, %1" : "+v"(pwA[4]), "+v"(pwA[6]));
        asm volatile("v_permlane32_swap_b32 %0, %1" : "+v"(pwA[5]), "+v"(pwA[7]));
        asm volatile("v_permlane32_swap_b32 %0, %1" : "+v"(pwB[0]), "+v"(pwB[2]));
        asm volatile("v_permlane32_swap_b32 %0, %1" : "+v"(pwB[1]), "+v"(pwB[3]));
        asm volatile("v_permlane32_swap_b32 %0, %1" : "+v"(pwB[4]), "+v"(pwB[6]));
        asm volatile("v_permlane32_swap_b32 %0, %1" : "+v"(pwB[5]), "+v"(pwB[7]));
        union { unsigned uu[4]; bf16x8 v; } pa0, pa1, pb0, pb1;
        pa0.uu[0] = pwA[0]; pa0.uu[1] = pwA[1]; pa0.uu[2] = pwA[2]; pa0.uu[3] = pwA[3];
        pa1.uu[0] = pwA[4]; pa1.uu[1] = pwA[5]; pa1.uu[2] = pwA[6]; pa1.uu[3] = pwA[7];
        pb0.uu[0] = pwB[0]; pb0.uu[1] = pwB[1]; pb0.uu[2] = pwB[2]; pb0.uu[3] = pwB[3];
        pb1.uu[0] = pwB[4]; pb1.uu[1] = pwB[5]; pb1.uu[2] = pwB[6]; pb1.uu[3] = pwB[7];

        __builtin_amdgcn_s_setprio(1);
        o0 = __builtin_amdgcn_mfma_f32_32x32x16_bf16(va[0],  pa0.v, o0, 0, 0, 0);
        o1 = __builtin_amdgcn_mfma_f32_32x32x16_bf16(vbf[0], pa0.v, o1, 0, 0, 0);
        o0 = __builtin_amdgcn_mfma_f32_32x32x16_bf16(va[1],  pa1.v, o0, 0, 0, 0);
        o1 = __builtin_amdgcn_mfma_f32_32x32x16_bf16(vbf[1], pa1.v, o1, 0, 0, 0);
        o0 = __builtin_amdgcn_mfma_f32_32x32x16_bf16(va[2],  pb0.v, o0, 0, 0, 0);
        o1 = __builtin_amdgcn_mfma_f32_32x32x16_bf16(vbf[2], pb0.v, o1, 0, 0, 0);
        o0 = __builtin_amdgcn_mfma_f32_32x32x16_bf16(va[3],  pb1.v, o0, 0, 0, 0);
        o1 = __builtin_amdgcn_mfma_f32_32x32x16_bf16(vbf[3], pb1.v, o1, 0, 0, 0);
        __builtin_amdgcn_s_setprio(0);
    }

    if (nW & 1) {   // tail single tile
        const int t = w1 - 1;
        const unsigned short* kb = KF + (size_t)t * 2048 + (size_t)lane * 8;
        const unsigned short* vb_ = VF + (size_t)t * 2048 + (size_t)lane * 8;
        bf16x8 kT[4];
        #pragma unroll
        for (int ks = 0; ks < 4; ++ks) kT[ks] = *(const bf16x8*)(kb + ks * 512);
        bf16x8 va0 = *(const bf16x8*)(vb_);
        bf16x8 va1 = *(const bf16x8*)(vb_ + 1024);
        bf16x8 vb0 = *(const bf16x8*)(vb_ + 512);
        bf16x8 vb1 = *(const bf16x8*)(vb_ + 1536);

        f32x16 sa;
        #pragma unroll
        for (int r = 0; r < 16; ++r) sa[r] = 0.f;
        __builtin_amdgcn_s_setprio(1);
        #pragma unroll
        for (int ks = 0; ks < 4; ++ks)
            sa = __builtin_amdgcn_mfma_f32_32x32x16_bf16(kT[ks], qf[ks], sa, 0, 0, 0);
        __builtin_amdgcn_s_setprio(0);

        float p0[16];
        #pragma unroll
        for (int r = 0; r < 16; ++r) p0[r] = sa[r] * SCL;
        if (t == qt) {
            #pragma unroll
            for (int r = 0; r < 16; ++r) {
                const int kvr = (r & 3) + 8 * (r >> 2) + 4 * hi;
                if (kvr > col) p0[r] = -1e30f;
            }
        }
        float tm = p0[0];
        #pragma unroll
        for (int r = 1; r < 16; ++r) tm = fmaxf(tm, p0[r]);
        tm = fmaxf(tm, __shfl_xor(tm, 32));
        if (!__all(tm <= m_i + 2.0f)) {
            const float mn = fmaxf(m_i, tm);
            const float alpha = EXP2(m_i - mn);
            m_i = mn;
            l_i *= alpha;
            #pragma unroll
            for (int r = 0; r < 16; ++r) { o0[r] *= alpha; o1[r] *= alpha; }
        }
        float rs = 0.f;
        #pragma unroll
        for (int r = 0; r < 16; ++r) { p0[r] = EXP2(p0[r] - m_i); rs += p0[r]; }
        rs += __shfl_xor(rs, 32);
        l_i += rs;

        unsigned pwA[8];
        #pragma unroll
        for (int i = 0; i < 8; ++i) pwA[i] = cvtpk(p0[2 * i], p0[2 * i + 1]);
        asm volatile("v_permlane32_swap_b32 %0, %1" : "+v"(pwA[0]), "+v"(pwA[2]));
        asm volatile("v_permlane32_swap_b32 %0, %1" : "+v"(pwA[1]), "+v"(pwA[3]));
        asm volatile("v_permlane32_swap_b32 %0, %1" : "+v"(pwA[4]), "+v"(pwA[6]));
        asm volatile("v_permlane32_swap_b32 %0, %1" : "+v"(pwA[5]), "+v"(pwA[7]));
        union { unsigned uu[4]; bf16x8 v; } pa0, pa1;
        pa0.uu[0] = pwA[0]; pa0.uu[1] = pwA[1]; pa0.uu[2] = pwA[2]; pa0.uu[3] = pwA[3];
        pa1.uu[0] = pwA[4]; pa1.uu[1] = pwA[5]; pa1.uu[2] = pwA[6]; pa1.uu[3] = pwA[7];

        __builtin_amdgcn_s_setprio(1);
        o0 = __builtin_amdgcn_mfma_f32_32x32x16_bf16(va0, pa0.v, o0, 0, 0, 0);
        o1 = __builtin_amdgcn_mfma_f32_32x32x16_bf16(vb0, pa0.v, o1, 0, 0, 0);
        o0 = __builtin_amdgcn_mfma_f32_32x32x16_bf16(va1, pa1.v, o0, 0, 0, 0);
        o1 = __builtin_amdgcn_mfma_f32_32x32x16_bf16(vb1, pa1.v, o1, 0, 0, 0);
        __builtin_amdgcn_s_setprio(0);
    }

    // per-wave partial -> LDS (O^T: lane col = q, regs = d)
    #pragma unroll
    for (int r = 0; r < 16; ++r) {
        const int d = (r & 3) + 8 * (r >> 2) + 4 * hi;
        Oall[w][col][d]      = o0[r];
        Oall[w][col][32 + d] = o1[r];
    }
    if (hi == 0) { Ml[w][col][0] = m_i; Ml[w][col][1] = l_i; }
    __syncthreads();

    // 2-barrier epilogue: tid<32 computes M, scl, L in one pass
    if (tid < 32) {
        float M = Ml[0][tid][0];
        #pragma unroll
        for (int w2 = 1; w2 < 4; ++w2) M = fmaxf(M, Ml[w2][tid][0]);
        float L = 0.f;
        #pragma unroll
        for (int w2 = 0; w2 < 4; ++w2) {
            const float sc = EXP2(Ml[w2][tid][0] - M);
            sScl[w2][tid] = sc;
            L += Ml[w2][tid][1] * sc;
        }
        sM[tid] = M;
        sL[tid] = L;
    }
    __syncthreads();

    const int r = tid >> 3;
    const int c0 = (tid & 7) * 8;
    f32x4 a0 = (f32x4){0.f, 0.f, 0.f, 0.f};
    f32x4 a1 = (f32x4){0.f, 0.f, 0.f, 0.f};
    #pragma unroll
    for (int w2 = 0; w2 < 4; ++w2) {
        const float sc = sScl[w2][r];
        const float* Orow = &Oall[w2][r][c0];
        a0 += (*(const f32x4*)(Orow)) * sc;
        a1 += (*(const f32x4*)(Orow + 4)) * sc;
    }
    if (qt < 32) {   // single chunk: final output
        const float inv = 1.f / sL[r];
        float* op = out + (size_t)(m0 + r) * DIM + c0;
        *(f32x4*)(op)     = a0 * inv;
        *(f32x4*)(op + 4) = a1 * inv;
    } else {         // partial for fixup
        const int pb = 16 * (g - 1) * (g + 2) + (qt - 32 * g) * (g + 1) + cid;
        float* op = Opart + (size_t)pb * 2048 + r * 64 + c0;
        *(f32x4*)(op)     = a0;
        *(f32x4*)(op + 4) = a1;
        if (tid < 32) {
            MLpart[(size_t)pb * 64 + tid * 2]     = sM[tid];
            MLpart[(size_t)pb * 64 + tid * 2 + 1] = sL[tid];
        }
    }
}

// ---- Fixup: merge chunk partials for qt >= 32. 224 blocks x 256 ------------
__global__ __launch_bounds__(256) void fixup_kernel(
    const float* __restrict__ Opart, const float* __restrict__ MLpart,
    float* __restrict__ out)
{
    __shared__ float sScl[8][32];
    __shared__ float sInvL[32];

    const int qt = 32 + (int)blockIdx.x;
    const int g  = qt >> 5;
    const int nc = g + 1;
    const int pb = 16 * (g - 1) * (g + 2) + (qt - 32 * g) * nc;
    const int tid = (int)threadIdx.x;

    if (tid < 32) {
        float M = -1e30f;
        for (int c2 = 0; c2 < nc; ++c2)
            M = fmaxf(M, MLpart[(size_t)(pb + c2) * 64 + tid * 2]);
        float L = 0.f;
        for (int c2 = 0; c2 < nc; ++c2) {
            const float sc = EXP2(MLpart[(size_t)(pb + c2) * 64 + tid * 2] - M);
            sScl[c2][tid] = sc;
            L += MLpart[(size_t)(pb + c2) * 64 + tid * 2 + 1] * sc;
        }
        sInvL[tid] = 1.f / L;
    }
    __syncthreads();

    const int r = tid >> 3;
    const int c0 = (tid & 7) * 8;
    f32x4 a0 = (f32x4){0.f, 0.f, 0.f, 0.f};
    f32x4 a1 = (f32x4){0.f, 0.f, 0.f, 0.f};
    for (int c2 = 0; c2 < nc; ++c2) {
        const float sc = sScl[c2][r];
        const float* Op = Opart + (size_t)(pb + c2) * 2048 + r * 64 + c0;
        a0 += (*(const f32x4*)(Op)) * sc;
        a1 += (*(const f32x4*)(Op + 4)) * sc;
    }
    const float inv = sInvL[r];
    float* op = out + (size_t)(qt * 32 + r) * DIM + c0;
    *(f32x4*)(op)     = a0 * inv;
    *(f32x4*)(op + 4) = a1 * inv;
}

extern "C" void kernel_launch(void* const* d_in, const int* in_sizes, int n_in,
                              void* d_out, int out_size, void* d_ws, size_t ws_size,
                              hipStream_t stream) {
    const float* x  = (const float*)d_in[0];
    const float* y  = (const float*)d_in[1];
    const float* z  = (const float*)d_in[2];
    const float* Wq = (const float*)d_in[3];
    const float* bq = (const float*)d_in[4];
    const float* Wk = (const float*)d_in[5];
    const float* bk = (const float*)d_in[6];
    const float* Wv = (const float*)d_in[7];
    const float* bv = (const float*)d_in[8];

    unsigned short* qkv = (unsigned short*)d_ws;
    unsigned short* Wt  = (unsigned short*)((char*)d_ws + 3145728);
    float* Opart        = (float*)((char*)d_ws + 3538944);
    float* MLpart       = (float*)((char*)d_ws + 12713984);
    float* out          = (float*)d_out;

    hipLaunchKernelGGL(wt_kernel,    dim3(48),   dim3(256), 0, stream, Wq, Wk, Wv, Wt);
    hipLaunchKernelGGL(proj_kernel,  dim3(768),  dim3(256), 0, stream, x, y, z, bq, bk, bv, Wt, qkv);
    hipLaunchKernelGGL(attn_kernel,  dim3(1152), dim3(256), 0, stream, qkv, out, Opart, MLpart);
    hipLaunchKernelGGL(fixup_kernel, dim3(224),  dim3(256), 0, stream, Opart, MLpart, out);
}

// Round 15
// 54.171 us; speedup vs baseline: 1.0975x; 1.0042x over previous
//
#include <hip/hip_runtime.h>

#define SEQ 8192
#define EMB 1024
#define DIM 64

typedef __attribute__((ext_vector_type(8))) short bf16x8;
typedef __attribute__((ext_vector_type(4))) float f32x4;
typedef __attribute__((ext_vector_type(16))) float f32x16;

#if __has_builtin(__builtin_amdgcn_exp2f)
#define EXP2 __builtin_amdgcn_exp2f
#else
#define EXP2 exp2f
#endif

// softmax scale folded with log2(e): (1/sqrt(8192)) * 1.4426950408889634
#define SCL 0.0159396779f

__device__ inline unsigned short f2bf(float f) {
    union { float f; unsigned u; } x; x.f = f;
    unsigned r = x.u + 0x7FFFu + ((x.u >> 16) & 1u);
    return (unsigned short)(r >> 16);
}

__device__ inline unsigned cvtpk(float lo, float hi) {
    unsigned r;
    asm("v_cvt_pk_bf16_f32 %0, %1, %2" : "=v"(r) : "v"(lo), "v"(hi));
    return r;
}

__device__ __forceinline__ void gload16(const float* g, float* l) {
    __builtin_amdgcn_global_load_lds(
        (const __attribute__((address_space(1))) unsigned*)g,
        (__attribute__((address_space(3))) unsigned*)l, 16, 0, 0);
}

// ---------------------------------------------------------------------------
// ws layout (bytes):
//  qkv @ 0        : q[8192][64] row-major | KF fragment | VF fragment  bf16
//  WF  @ 3145728  : [3][32 sg][4 wc][64 lane][8] bf16 fragment layout (393,216)
//  Opart @ 3538944 : [1120][32][64] f32 (9,175,040)
//  MLpart @ 12713984 : [1120][32][2] f32 (286,720)
// ---------------------------------------------------------------------------

// ---- W -> bf16 fragment layout, COALESCED (LDS transpose) ------------------
__global__ __launch_bounds__(256) void wt_kernel(
    const float* __restrict__ Wq, const float* __restrict__ Wk,
    const float* __restrict__ Wv, unsigned short* __restrict__ Wt)
{
    __shared__ float L[64][65];

    const int b   = (int)blockIdx.x;   // 0..47
    const int mat = b >> 4;
    const int kt  = b & 15;
    const float* W = (mat == 0) ? Wq : (mat == 1) ? Wk : Wv;
    const int tid = (int)threadIdx.x;

    const float* src = W + (size_t)kt * 64 * DIM;   // 64 rows x 64 cols
    #pragma unroll
    for (int i = 0; i < 16; ++i) {
        const int idx = i * 256 + tid;
        L[idx >> 6][idx & 63] = src[idx];
    }
    __syncthreads();

    unsigned short* dst = Wt + (size_t)(mat * 32 + kt * 2) * 2048;
    #pragma unroll
    for (int h = 0; h < 2; ++h) {
        const int s = tid * 16 + h * 8;          // short index, mult of 8
        const int sgo   = s >> 11;               // 0..1
        const int wcg   = (s >> 9) & 3;
        const int lanep = (s >> 3) & 63;
        const int qq = lanep >> 4, c = lanep & 15;
        const int kb = sgo * 32 + qq * 8;
        const int n  = wcg * 16 + c;
        uint4 w4;
        w4.x = cvtpk(L[kb + 0][n], L[kb + 1][n]);
        w4.y = cvtpk(L[kb + 2][n], L[kb + 3][n]);
        w4.z = cvtpk(L[kb + 4][n], L[kb + 5][n]);
        w4.w = cvtpk(L[kb + 6][n], L[kb + 7][n]);
        *(uint4*)&dst[s] = w4;
    }
}

__device__ inline bf16x8 cvt8(float4 a, float4 b) {
    union { unsigned u[4]; bf16x8 v; } r;
    r.u[0] = cvtpk(a.x, a.y);
    r.u[1] = cvtpk(a.z, a.w);
    r.u[2] = cvtpk(b.x, b.y);
    r.u[3] = cvtpk(b.z, b.w);
    return r.v;
}

// ---- Projection: barrier-free per-wave streaming, HIGH-OCCUPANCY -----------
// 1536 blocks x 256 thr (4 waves). Block = 16 rows x 64 cols, 4-way K-split.
// Wave kq owns 16 rows x K-quarter(256); window = 32-K tile {2 X-gload,
// 4 W-load} = 6, depth-3 (vmcnt(12) steady, 6/0 drain), wave-private LDS
// 3 bufs x 2 KB x 4 waves = 24 KB -> 6 blocks/CU; grid = exactly 6/CU.
// launch_bounds(256,4): VGPR cap 128 (need ~115). Watch FETCH for spill.
__global__ __launch_bounds__(256, 4) void proj_kernel(
    const float* __restrict__ x, const float* __restrict__ y, const float* __restrict__ z,
    const float* __restrict__ bq, const float* __restrict__ bk, const float* __restrict__ bv,
    const unsigned short* __restrict__ Wt, unsigned short* __restrict__ qkv)
{
    __shared__ float pool[6144];   // 24 KB: 4 waves x 3 bufs x 512 f32

    const int bid = (int)blockIdx.x;
    const int mat = bid >> 9;                 // 0=q,1=k,2=v (512 blocks each)
    const int rb  = (bid & 511) * 16;

    const int tid  = (int)threadIdx.x;
    const int lane = tid & 63;
    const int kq   = tid >> 6;                // K-quarter 0..3
    const int c    = lane & 15;
    const int qq   = lane >> 4;

    const float* X  = (mat == 0) ? x  : (mat == 1) ? y  : z;
    const float* Bv = (mat == 0) ? bq : (mat == 1) ? bk : bv;
    const unsigned short* Wm = Wt + (size_t)mat * 65536;
    unsigned short* outp = qkv + (size_t)mat * (SEQ * DIM);

    float* poolw = pool + kq * 1536;
    const float* Xw = X + (size_t)rb * EMB + kq * 256;

    f32x4 acc[4];
    #pragma unroll
    for (int i = 0; i < 4; ++i) acc[i] = (f32x4){0.f, 0.f, 0.f, 0.f};

    bf16x8 wreg[3][4];

    // window t: 2 X-gloads (1 KB each: 8 rows x 128B, XOR-preswizzled source)
    //           + 4 W-frag loads (lane-contiguous)
    #define STAGE(buf, t)                                                       \
        {                                                                       \
            const int k0_ = (t) * 32;                                           \
            _Pragma("unroll")                                                   \
            for (int j = 0; j < 2; ++j) {                                       \
                const int rloc = j * 8 + (lane >> 3);                           \
                const int g = (lane & 7) ^ (rloc & 7);                          \
                gload16(Xw + (size_t)rloc * EMB + k0_ + g * 4,                  \
                        poolw + (buf) * 512 + j * 256);                         \
            }                                                                   \
        }
    #define WLOAD(slot, t)                                                      \
        {                                                                       \
            const int sg_ = kq * 8 + (t);                                       \
            _Pragma("unroll")                                                   \
            for (int wc2 = 0; wc2 < 4; ++wc2)                                   \
                wreg[slot][wc2] = *(const bf16x8*)(Wm +                         \
                    ((size_t)(sg_ * 4 + wc2) * 64 + lane) * 8);                 \
        }
    #define COMP(bt)                                                            \
        {                                                                       \
            const float* rowb = poolw + (bt) * 512 + c * 32;                    \
            float4 fa = *(const float4*)(rowb + (((qq * 2)     ^ (c & 7)) << 2)); \
            float4 fb = *(const float4*)(rowb + (((qq * 2 + 1) ^ (c & 7)) << 2)); \
            bf16x8 af = cvt8(fa, fb);                                           \
            _Pragma("unroll")                                                   \
            for (int wc2 = 0; wc2 < 4; ++wc2)                                   \
                acc[wc2] = __builtin_amdgcn_mfma_f32_16x16x32_bf16(             \
                    af, wreg[bt][wc2], acc[wc2], 0, 0, 0);                      \
        }

    // prologue: windows 0,1,2 (FIFO order pinned by memory clobbers)
    STAGE(0, 0); WLOAD(0, 0);
    asm volatile("" ::: "memory");
    STAGE(1, 1); WLOAD(1, 1);
    asm volatile("" ::: "memory");
    STAGE(2, 2); WLOAD(2, 2);

    #pragma unroll
    for (int t = 0; t < 8; ++t) {
        if (t <= 5)      asm volatile("s_waitcnt vmcnt(12)" ::: "memory");
        else if (t == 6) asm volatile("s_waitcnt vmcnt(6)"  ::: "memory");
        else             asm volatile("s_waitcnt vmcnt(0)"  ::: "memory");
        COMP(t % 3);
        if (t < 5) { STAGE(t % 3, t + 3); WLOAD(t % 3, t + 3); }
    }
    #undef STAGE
    #undef WLOAD
    #undef COMP

    // ---- combine K-quarters (reuse pool) ----
    __syncthreads();
    float (*part)[16][68] = (float (*)[16][68])pool;   // 4x16x68 = 4352 f32
    #pragma unroll
    for (int wc2 = 0; wc2 < 4; ++wc2)
        #pragma unroll
        for (int i = 0; i < 4; ++i)
            part[kq][qq * 4 + i][wc2 * 16 + c] = acc[wc2][i];
    __syncthreads();

    const int T2 = rb >> 5;           // 32-row fragment tile
    const int cb = rb & 31;           // 0 or 16 within it
    if (mat == 0) {                     // q row-major: uint2/thread
        const int row = tid >> 4;
        const int c0  = (tid & 15) * 4;
        float v0 = part[0][row][c0+0] + part[1][row][c0+0] + part[2][row][c0+0] + part[3][row][c0+0] + Bv[c0+0];
        float v1 = part[0][row][c0+1] + part[1][row][c0+1] + part[2][row][c0+1] + part[3][row][c0+1] + Bv[c0+1];
        float v2 = part[0][row][c0+2] + part[1][row][c0+2] + part[2][row][c0+2] + part[3][row][c0+2] + Bv[c0+2];
        float v3 = part[0][row][c0+3] + part[1][row][c0+3] + part[2][row][c0+3] + part[3][row][c0+3] + Bv[c0+3];
        uint2 pk;
        pk.x = cvtpk(v0, v1); pk.y = cvtpk(v2, v3);
        *(uint2*)&outp[(size_t)(rb + row) * DIM + c0] = pk;
    } else if (mat == 1) {              // KF: elem ((T2*4+ks)*2+hi)*256 + col*8 + j
        const int ks  = tid >> 7;            // wait: need 2 bits
        const int ks2 = (tid >> 7) & 1;      // combine with below
        const int kss = tid >> 7;            // 0..1 only — use full mapping:
        (void)ks; (void)ks2; (void)kss;
        // tid = ((ks*2 + hi)*16 + cl)*2 + jh ; ks 0..3, hi 0..1, cl 0..15, jh 0..1
        const int jh = tid & 1;
        const int cl = (tid >> 1) & 15;
        const int hi2 = (tid >> 5) & 1;
        const int ksf = tid >> 6;            // 0..3
        const int d0 = ksf * 16 + hi2 * 8 + jh * 4;
        float v0 = part[0][cl][d0+0] + part[1][cl][d0+0] + part[2][cl][d0+0] + part[3][cl][d0+0] + Bv[d0+0];
        float v1 = part[0][cl][d0+1] + part[1][cl][d0+1] + part[2][cl][d0+1] + part[3][cl][d0+1] + Bv[d0+1];
        float v2 = part[0][cl][d0+2] + part[1][cl][d0+2] + part[2][cl][d0+2] + part[3][cl][d0+2] + Bv[d0+2];
        float v3 = part[0][cl][d0+3] + part[1][cl][d0+3] + part[2][cl][d0+3] + part[3][cl][d0+3] + Bv[d0+3];
        const size_t base = ((size_t)(T2 * 4 + ksf) * 2 + hi2) * 256 + (size_t)(cb + cl) * 8 + jh * 4;
        uint2 pk;
        pk.x = cvtpk(v0, v1); pk.y = cvtpk(v2, v3);
        *(uint2*)&outp[base] = pk;
    } else {                            // VF: elem ((T2*2+i)*2+h)*512 + (hi*32+col)*8 + j
        const int jh  = tid & 1;
        const int col = (tid >> 1) & 31;
        const int hi2 = (tid >> 6) & 1;
        const int h   = tid >> 7;
        const int i2  = cb >> 4;
        const int cv  = h * 32 + col;
        const float bb = Bv[cv];
        const int r0 = hi2 * 8 + jh * 4;
        float v0 = part[0][r0+0][cv] + part[1][r0+0][cv] + part[2][r0+0][cv] + part[3][r0+0][cv] + bb;
        float v1 = part[0][r0+1][cv] + part[1][r0+1][cv] + part[2][r0+1][cv] + part[3][r0+1][cv] + bb;
        float v2 = part[0][r0+2][cv] + part[1][r0+2][cv] + part[2][r0+2][cv] + part[3][r0+2][cv] + bb;
        float v3 = part[0][r0+3][cv] + part[1][r0+3][cv] + part[2][r0+3][cv] + part[3][r0+3][cv] + bb;
        const size_t base = ((size_t)(T2 * 2 + i2) * 2 + h) * 512 + (size_t)(hi2 * 32 + col) * 8 + jh * 4;
        uint2 pk;
        pk.x = cvtpk(v0, v1); pk.y = cvtpk(v2, v3);
        *(uint2*)&outp[base] = pk;
    }
}

// ---- Flash attention: swapped-operand 32x32, KVBLK=64 pairs, defer-max -----
// 1152 blocks x 256 thr (4 waves). Unit = (qtile, 32-tile KV chunk).
// Software-pipelined: next pair's K prefetched after current QK; V loads
// after QK (wait hides under softmax). launch_bounds (256,3): DO NOT raise
// to 4 (R8: VGPR cap -> spill, FETCH 9.5->68 MB).
__global__ __launch_bounds__(256, 3) void attn_kernel(
    const unsigned short* __restrict__ qkv, float* __restrict__ out,
    float* __restrict__ Opart, float* __restrict__ MLpart)
{
    const unsigned short* Q  = qkv;
    const unsigned short* KF = qkv + SEQ * DIM;
    const unsigned short* VF = qkv + 2 * SEQ * DIM;

    __shared__ float Oall[4][32][68];
    __shared__ float Ml[4][32][2];
    __shared__ float sScl[4][32];
    __shared__ float sM[32];
    __shared__ float sL[32];

    // unit id, longest-first
    const int u = 1151 - (int)blockIdx.x;
    int g;
    if (u < 32) g = 0; else if (u < 96) g = 1; else if (u < 192) g = 2;
    else if (u < 320) g = 3; else if (u < 480) g = 4; else if (u < 672) g = 5;
    else if (u < 896) g = 6; else g = 7;
    const int o_  = u - 16 * g * (g + 1);
    const int qt  = 32 * g + o_ / (g + 1);
    const int cid = o_ - (o_ / (g + 1)) * (g + 1);

    const int m0 = qt * 32;
    const int tid = (int)threadIdx.x;
    const int lane = tid & 63;
    const int w = tid >> 6;        // 0..3
    const int col = lane & 31;     // q row within tile
    const int hi = lane >> 5;

    bf16x8 qf[4];
    {
        const unsigned short* Qr = Q + (size_t)(m0 + col) * DIM + hi * 8;
        #pragma unroll
        for (int ks = 0; ks < 4; ++ks) qf[ks] = *(const bf16x8*)(Qr + ks * 16);
    }

    f32x16 o0, o1;
    #pragma unroll
    for (int r = 0; r < 16; ++r) { o0[r] = 0.f; o1[r] = 0.f; }
    float m_i = -1e30f, l_i = 0.f;

    const int nT = qt + 1;
    const int tb = cid * 32;
    const int te = (tb + 32 < nT) ? (tb + 32) : nT;
    const int nC = te - tb;
    const int w0 = tb + ((nC * w) >> 2);
    const int w1 = tb + ((nC * (w + 1)) >> 2);
    const int nW = w1 - w0;
    const int nP = nW >> 1;

    // ---- K prefetch for the first pair ----
    bf16x8 kA[4], kB[4];
    if (nP > 0) {
        const unsigned short* kb0 = KF + (size_t)w0 * 2048 + (size_t)lane * 8;
        #pragma unroll
        for (int ks = 0; ks < 4; ++ks) kA[ks] = *(const bf16x8*)(kb0 + ks * 512);
        #pragma unroll
        for (int ks = 0; ks < 4; ++ks) kB[ks] = *(const bf16x8*)(kb0 + 2048 + ks * 512);
    }

    for (int pi = 0; pi < nP; ++pi) {
        const int t = w0 + 2 * pi;

        // ---- dual QK chains (consume kA/kB) ----
        f32x16 sa, sb;
        #pragma unroll
        for (int r = 0; r < 16; ++r) { sa[r] = 0.f; sb[r] = 0.f; }
        __builtin_amdgcn_s_setprio(1);
        #pragma unroll
        for (int ks = 0; ks < 4; ++ks) {
            sa = __builtin_amdgcn_mfma_f32_32x32x16_bf16(kA[ks], qf[ks], sa, 0, 0, 0);
            sb = __builtin_amdgcn_mfma_f32_32x32x16_bf16(kB[ks], qf[ks], sb, 0, 0, 0);
        }
        __builtin_amdgcn_s_setprio(0);

        // ---- prefetch next pair's K (regs dead after QK) ----
        if (pi + 1 < nP) {
            const unsigned short* kbn = KF + (size_t)(t + 2) * 2048 + (size_t)lane * 8;
            #pragma unroll
            for (int ks = 0; ks < 4; ++ks) kA[ks] = *(const bf16x8*)(kbn + ks * 512);
            #pragma unroll
            for (int ks = 0; ks < 4; ++ks) kB[ks] = *(const bf16x8*)(kbn + 2048 + ks * 512);
        }

        // ---- V loads issued here; wait falls before PV (under softmax) ----
        const unsigned short* vb_ = VF + (size_t)t * 2048 + (size_t)lane * 8;
        bf16x8 va[4], vbf[4];
        #pragma unroll
        for (int i = 0; i < 4; ++i) va[i]  = *(const bf16x8*)(vb_ + i * 1024);
        #pragma unroll
        for (int i = 0; i < 4; ++i) vbf[i] = *(const bf16x8*)(vb_ + 512 + i * 1024);

        float p0[16], p1[16];
        #pragma unroll
        for (int r = 0; r < 16; ++r) { p0[r] = sa[r] * SCL; p1[r] = sb[r] * SCL; }
        if (t + 1 == qt) {   // diagonal can only be the second tile of a pair
            #pragma unroll
            for (int r = 0; r < 16; ++r) {
                const int kvr = (r & 3) + 8 * (r >> 2) + 4 * hi;
                if (kvr > col) p1[r] = -1e30f;
            }
        }
        float tm = fmaxf(p0[0], p1[0]);
        #pragma unroll
        for (int r = 1; r < 16; ++r) tm = fmaxf(tm, fmaxf(p0[r], p1[r]));
        tm = fmaxf(tm, __shfl_xor(tm, 32));
        if (!__all(tm <= m_i + 2.0f)) {
            const float mn = fmaxf(m_i, tm);
            const float alpha = EXP2(m_i - mn);
            m_i = mn;
            l_i *= alpha;
            #pragma unroll
            for (int r = 0; r < 16; ++r) { o0[r] *= alpha; o1[r] *= alpha; }
        }
        float rs = 0.f;
        #pragma unroll
        for (int r = 0; r < 16; ++r) { p0[r] = EXP2(p0[r] - m_i); rs += p0[r]; }
        #pragma unroll
        for (int r = 0; r < 16; ++r) { p1[r] = EXP2(p1[r] - m_i); rs += p1[r]; }
        rs += __shfl_xor(rs, 32);
        l_i += rs;

        unsigned pwA[8], pwB[8];
        #pragma unroll
        for (int i = 0; i < 8; ++i) pwA[i] = cvtpk(p0[2 * i], p0[2 * i + 1]);
        #pragma unroll
        for (int i = 0; i < 8; ++i) pwB[i] = cvtpk(p1[2 * i], p1[2 * i + 1]);
        asm volatile("v_permlane32_swap_b32 %0, %1" : "+v"(pwA[0]), "+v"(pwA[2]));
        asm volatile("v_permlane32_swap_b32 %0, %1" : "+v"(pwA[1]), "+v"(pwA[3]));
        asm volatile("v_permlane32_swap_b32 %0, %1" : "+v"(pwA[4]), "+v"(pwA[6]));
        asm volatile("v_permlane32_swap_b32 %0, %1" : "+v"(pwA[5]), "+v"(pwA[7]));
        asm volatile("v_permlane32_swap_b32 %0, %1" : "+v"(pwB[0]), "+v"(pwB[2]));
        asm volatile("v_permlane32_swap_b32 %0, %1" : "+v"(pwB[1]), "+v"(pwB[3]));
        asm volatile("v_permlane32_swap_b32 %0, %1" : "+v"(pwB[4]), "+v"(pwB[6]));
        asm volatile("v_permlane32_swap_b32 %0, %1" : "+v"(pwB[5]), "+v"(pwB[7]));
        union { unsigned uu[4]; bf16x8 v; } pa0, pa1, pb0, pb1;
        pa0.uu[0] = pwA[0]; pa0.uu[1] = pwA[1]; pa0.uu[2] = pwA[2]; pa0.uu[3] = pwA[3];
        pa1.uu[0] = pwA[4]; pa1.uu[1] = pwA[5]; pa1.uu[2] = pwA[6]; pa1.uu[3] = pwA[7];
        pb0.uu[0] = pwB[0]; pb0.uu[1] = pwB[1]; pb0.uu[2] = pwB[2]; pb0.uu[3] = pwB[3];
        pb1.uu[0] = pwB[4]; pb1.uu[1] = pwB[5]; pb1.uu[2] = pwB[6]; pb1.uu[3] = pwB[7];

        __builtin_amdgcn_s_setprio(1);
        o0 = __builtin_amdgcn_mfma_f32_32x32x16_bf16(va[0],  pa0.v, o0, 0, 0, 0);
        o1 = __builtin_amdgcn_mfma_f32_32x32x16_bf16(vbf[0], pa0.v, o1, 0, 0, 0);
        o0 = __builtin_amdgcn_mfma_f32_32x32x16_bf16(va[1],  pa1.v, o0, 0, 0, 0);
        o1 = __builtin_amdgcn_mfma_f32_32x32x16_bf16(vbf[1], pa1.v, o1, 0, 0, 0);
        o0 = __builtin_amdgcn_mfma_f32_32x32x16_bf16(va[2],  pb0.v, o0, 0, 0, 0);
        o1 = __builtin_amdgcn_mfma_f32_32x32x16_bf16(vbf[2], pb0.v, o1, 0, 0, 0);
        o0 = __builtin_amdgcn_mfma_f32_32x32x16_bf16(va[3],  pb1.v, o0, 0, 0, 0);
        o1 = __builtin_amdgcn_mfma_f32_32x32x16_bf16(vbf[3], pb1.v, o1, 0, 0, 0);
        __builtin_amdgcn_s_setprio(0);
    }

    if (nW & 1) {   // tail single tile
        const int t = w1 - 1;
        const unsigned short* kb = KF + (size_t)t * 2048 + (size_t)lane * 8;
        const unsigned short* vb_ = VF + (size_t)t * 2048 + (size_t)lane * 8;
        bf16x8 kT[4];
        #pragma unroll
        for (int ks = 0; ks < 4; ++ks) kT[ks] = *(const bf16x8*)(kb + ks * 512);
        bf16x8 va0 = *(const bf16x8*)(vb_);
        bf16x8 va1 = *(const bf16x8*)(vb_ + 1024);
        bf16x8 vb0 = *(const bf16x8*)(vb_ + 512);
        bf16x8 vb1 = *(const bf16x8*)(vb_ + 1536);

        f32x16 sa;
        #pragma unroll
        for (int r = 0; r < 16; ++r) sa[r] = 0.f;
        __builtin_amdgcn_s_setprio(1);
        #pragma unroll
        for (int ks = 0; ks < 4; ++ks)
            sa = __builtin_amdgcn_mfma_f32_32x32x16_bf16(kT[ks], qf[ks], sa, 0, 0, 0);
        __builtin_amdgcn_s_setprio(0);

        float p0[16];
        #pragma unroll
        for (int r = 0; r < 16; ++r) p0[r] = sa[r] * SCL;
        if (t == qt) {
            #pragma unroll
            for (int r = 0; r < 16; ++r) {
                const int kvr = (r & 3) + 8 * (r >> 2) + 4 * hi;
                if (kvr > col) p0[r] = -1e30f;
            }
        }
        float tm = p0[0];
        #pragma unroll
        for (int r = 1; r < 16; ++r) tm = fmaxf(tm, p0[r]);
        tm = fmaxf(tm, __shfl_xor(tm, 32));
        if (!__all(tm <= m_i + 2.0f)) {
            const float mn = fmaxf(m_i, tm);
            const float alpha = EXP2(m_i - mn);
            m_i = mn;
            l_i *= alpha;
            #pragma unroll
            for (int r = 0; r < 16; ++r) { o0[r] *= alpha; o1[r] *= alpha; }
        }
        float rs = 0.f;
        #pragma unroll
        for (int r = 0; r < 16; ++r) { p0[r] = EXP2(p0[r] - m_i); rs += p0[r]; }
        rs += __shfl_xor(rs, 32);
        l_i += rs;

        unsigned pwA[8];
        #pragma unroll
        for (int i = 0; i < 8; ++i) pwA[i] = cvtpk(p0[2 * i], p0[2 * i + 1]);
        asm volatile("v_permlane32_swap_b32 %0, %1" : "+v"(pwA[0]), "+v"(pwA[2]));
        asm volatile("v_permlane32_swap_b32 %0, %1" : "+v"(pwA[1]), "+v"(pwA[3]));
        asm volatile("v_permlane32_swap_b32 %0, %1" : "+v"(pwA[4]), "+v"(pwA[6]));
        asm volatile("v_permlane32_swap_b32 %0, %1" : "+v"(pwA[5]), "+v"(pwA[7]));
        union { unsigned uu[4]; bf16x8 v; } pa0, pa1;
        pa0.uu[0] = pwA[0]; pa0.uu[1] = pwA[1]; pa0.uu[2] = pwA[2]; pa0.uu[3] = pwA[3];
        pa1.uu[0] = pwA[4]; pa1.uu[1] = pwA[5]; pa1.uu[2] = pwA[6]; pa1.uu[3] = pwA[7];

        __builtin_amdgcn_s_setprio(1);
        o0 = __builtin_amdgcn_mfma_f32_32x32x16_bf16(va0, pa0.v, o0, 0, 0, 0);
        o1 = __builtin_amdgcn_mfma_f32_32x32x16_bf16(vb0, pa0.v, o1, 0, 0, 0);
        o0 = __builtin_amdgcn_mfma_f32_32x32x16_bf16(va1, pa1.v, o0, 0, 0, 0);
        o1 = __builtin_amdgcn_mfma_f32_32x32x16_bf16(vb1, pa1.v, o1, 0, 0, 0);
        __builtin_amdgcn_s_setprio(0);
    }

    // per-wave partial -> LDS (O^T: lane col = q, regs = d)
    #pragma unroll
    for (int r = 0; r < 16; ++r) {
        const int d = (r & 3) + 8 * (r >> 2) + 4 * hi;
        Oall[w][col][d]      = o0[r];
        Oall[w][col][32 + d] = o1[r];
    }
    if (hi == 0) { Ml[w][col][0] = m_i; Ml[w][col][1] = l_i; }
    __syncthreads();

    // 2-barrier epilogue: tid<32 computes M, scl, L in one pass
    if (tid < 32) {
        float M = Ml[0][tid][0];
        #pragma unroll
        for (int w2 = 1; w2 < 4; ++w2) M = fmaxf(M, Ml[w2][tid][0]);
        float L = 0.f;
        #pragma unroll
        for (int w2 = 0; w2 < 4; ++w2) {
            const float sc = EXP2(Ml[w2][tid][0] - M);
            sScl[w2][tid] = sc;
            L += Ml[w2][tid][1] * sc;
        }
        sM[tid] = M;
        sL[tid] = L;
    }
    __syncthreads();

    const int r = tid >> 3;
    const int c0 = (tid & 7) * 8;
    f32x4 a0 = (f32x4){0.f, 0.f, 0.f, 0.f};
    f32x4 a1 = (f32x4){0.f, 0.f, 0.f, 0.f};
    #pragma unroll
    for (int w2 = 0; w2 < 4; ++w2) {
        const float sc = sScl[w2][r];
        const float* Orow = &Oall[w2][r][c0];
        a0 += (*(const f32x4*)(Orow)) * sc;
        a1 += (*(const f32x4*)(Orow + 4)) * sc;
    }
    if (qt < 32) {   // single chunk: final output
        const float inv = 1.f / sL[r];
        float* op = out + (size_t)(m0 + r) * DIM + c0;
        *(f32x4*)(op)     = a0 * inv;
        *(f32x4*)(op + 4) = a1 * inv;
    } else {         // partial for fixup
        const int pb = 16 * (g - 1) * (g + 2) + (qt - 32 * g) * (g + 1) + cid;
        float* op = Opart + (size_t)pb * 2048 + r * 64 + c0;
        *(f32x4*)(op)     = a0;
        *(f32x4*)(op + 4) = a1;
        if (tid < 32) {
            MLpart[(size_t)pb * 64 + tid * 2]     = sM[tid];
            MLpart[(size_t)pb * 64 + tid * 2 + 1] = sL[tid];
        }
    }
}

// ---- Fixup: merge chunk partials for qt >= 32. 224 blocks x 256 ------------
__global__ __launch_bounds__(256) void fixup_kernel(
    const float* __restrict__ Opart, const float* __restrict__ MLpart,
    float* __restrict__ out)
{
    __shared__ float sScl[8][32];
    __shared__ float sInvL[32];

    const int qt = 32 + (int)blockIdx.x;
    const int g  = qt >> 5;
    const int nc = g + 1;
    const int pb = 16 * (g - 1) * (g + 2) + (qt - 32 * g) * nc;
    const int tid = (int)threadIdx.x;

    if (tid < 32) {
        float M = -1e30f;
        for (int c2 = 0; c2 < nc; ++c2)
            M = fmaxf(M, MLpart[(size_t)(pb + c2) * 64 + tid * 2]);
        float L = 0.f;
        for (int c2 = 0; c2 < nc; ++c2) {
            const float sc = EXP2(MLpart[(size_t)(pb + c2) * 64 + tid * 2] - M);
            sScl[c2][tid] = sc;
            L += MLpart[(size_t)(pb + c2) * 64 + tid * 2 + 1] * sc;
        }
        sInvL[tid] = 1.f / L;
    }
    __syncthreads();

    const int r = tid >> 3;
    const int c0 = (tid & 7) * 8;
    f32x4 a0 = (f32x4){0.f, 0.f, 0.f, 0.f};
    f32x4 a1 = (f32x4){0.f, 0.f, 0.f, 0.f};
    for (int c2 = 0; c2 < nc; ++c2) {
        const float sc = sScl[c2][r];
        const float* Op = Opart + (size_t)(pb + c2) * 2048 + r * 64 + c0;
        a0 += (*(const f32x4*)(Op)) * sc;
        a1 += (*(const f32x4*)(Op + 4)) * sc;
    }
    const float inv = sInvL[r];
    float* op = out + (size_t)(qt * 32 + r) * DIM + c0;
    *(f32x4*)(op)     = a0 * inv;
    *(f32x4*)(op + 4) = a1 * inv;
}

extern "C" void kernel_launch(void* const* d_in, const int* in_sizes, int n_in,
                              void* d_out, int out_size, void* d_ws, size_t ws_size,
                              hipStream_t stream) {
    const float* x  = (const float*)d_in[0];
    const float* y  = (const float*)d_in[1];
    const float* z  = (const float*)d_in[2];
    const float* Wq = (const float*)d_in[3];
    const float* bq = (const float*)d_in[4];
    const float* Wk = (const float*)d_in[5];
    const float* bk = (const float*)d_in[6];
    const float* Wv = (const float*)d_in[7];
    const float* bv = (const float*)d_in[8];

    unsigned short* qkv = (unsigned short*)d_ws;
    unsigned short* Wt  = (unsigned short*)((char*)d_ws + 3145728);
    float* Opart        = (float*)((char*)d_ws + 3538944);
    float* MLpart       = (float*)((char*)d_ws + 12713984);
    float* out          = (float*)d_out;

    hipLaunchKernelGGL(wt_kernel,    dim3(48),   dim3(256), 0, stream, Wq, Wk, Wv, Wt);
    hipLaunchKernelGGL(proj_kernel,  dim3(1536), dim3(256), 0, stream, x, y, z, bq, bk, bv, Wt, qkv);
    hipLaunchKernelGGL(attn_kernel,  dim3(1152), dim3(256), 0, stream, qkv, out, Opart, MLpart);
    hipLaunchKernelGGL(fixup_kernel, dim3(224),  dim3(256), 0, stream, Opart, MLpart, out);
}

// Round 16
// 54.058 us; speedup vs baseline: 1.0998x; 1.0021x over previous
//
#include <hip/hip_runtime.h>

#define SEQ 8192
#define EMB 1024
#define DIM 64

typedef __attribute__((ext_vector_type(8))) short bf16x8;
typedef __attribute__((ext_vector_type(4))) float f32x4;
typedef __attribute__((ext_vector_type(16))) float f32x16;

#if __has_builtin(__builtin_amdgcn_exp2f)
#define EXP2 __builtin_amdgcn_exp2f
#else
#define EXP2 exp2f
#endif

// softmax scale folded with log2(e): (1/sqrt(8192)) * 1.4426950408889634
#define SCL 0.0159396779f

__device__ inline unsigned short f2bf(float f) {
    union { float f; unsigned u; } x; x.f = f;
    unsigned r = x.u + 0x7FFFu + ((x.u >> 16) & 1u);
    return (unsigned short)(r >> 16);
}

__device__ inline unsigned cvtpk(float lo, float hi) {
    unsigned r;
    asm("v_cvt_pk_bf16_f32 %0, %1, %2" : "=v"(r) : "v"(lo), "v"(hi));
    return r;
}

__device__ __forceinline__ void gload16(const float* g, float* l) {
    __builtin_amdgcn_global_load_lds(
        (const __attribute__((address_space(1))) unsigned*)g,
        (__attribute__((address_space(3))) unsigned*)l, 16, 0, 0);
}

// ---------------------------------------------------------------------------
// ws layout (bytes):
//  qkv @ 0        : q[8192][64] row-major | KF fragment | VF fragment  bf16
//  WF  @ 3145728  : [3][32 sg][4 wc][64 lane][8] bf16 fragment layout (393,216)
//  Opart @ 3538944 : [1120][32][64] f32 (9,175,040)
//  MLpart @ 12713984 : [1120][32][2] f32 (286,720)
// ---------------------------------------------------------------------------

// ---- W -> bf16 fragment layout, COALESCED (LDS transpose) ------------------
__global__ __launch_bounds__(256) void wt_kernel(
    const float* __restrict__ Wq, const float* __restrict__ Wk,
    const float* __restrict__ Wv, unsigned short* __restrict__ Wt)
{
    __shared__ float L[64][65];

    const int b   = (int)blockIdx.x;   // 0..47
    const int mat = b >> 4;
    const int kt  = b & 15;
    const float* W = (mat == 0) ? Wq : (mat == 1) ? Wk : Wv;
    const int tid = (int)threadIdx.x;

    const float* src = W + (size_t)kt * 64 * DIM;   // 64 rows x 64 cols
    #pragma unroll
    for (int i = 0; i < 16; ++i) {
        const int idx = i * 256 + tid;
        L[idx >> 6][idx & 63] = src[idx];
    }
    __syncthreads();

    unsigned short* dst = Wt + (size_t)(mat * 32 + kt * 2) * 2048;
    #pragma unroll
    for (int h = 0; h < 2; ++h) {
        const int s = tid * 16 + h * 8;          // short index, mult of 8
        const int sgo   = s >> 11;               // 0..1
        const int wcg   = (s >> 9) & 3;
        const int lanep = (s >> 3) & 63;
        const int qq = lanep >> 4, c = lanep & 15;
        const int kb = sgo * 32 + qq * 8;
        const int n  = wcg * 16 + c;
        uint4 w4;
        w4.x = cvtpk(L[kb + 0][n], L[kb + 1][n]);
        w4.y = cvtpk(L[kb + 2][n], L[kb + 3][n]);
        w4.z = cvtpk(L[kb + 4][n], L[kb + 5][n]);
        w4.w = cvtpk(L[kb + 6][n], L[kb + 7][n]);
        *(uint4*)&dst[s] = w4;
    }
}

__device__ inline bf16x8 cvt8(float4 a, float4 b) {
    union { unsigned u[4]; bf16x8 v; } r;
    r.u[0] = cvtpk(a.x, a.y);
    r.u[1] = cvtpk(a.z, a.w);
    r.u[2] = cvtpk(b.x, b.y);
    r.u[3] = cvtpk(b.z, b.w);
    return r.v;
}

// ---- Projection: barrier-free per-wave streaming, W AMORTIZED x2 -----------
// 768 blocks x 256 thr (4 waves). Block = 32 rows (2 row-groups of 16) x 64
// cols, 4-way K-split. Wave kq owns K-quarter(256) for BOTH row-groups; W
// fragments loaded once per window and reused for both groups (W L2 traffic
// 192 -> 98 MB). Window = {4 X-gload, 4 W-load} = 8, depth-3: vmcnt(16)
// steady, 8 @ t=6, 0 @ t=7. Wave-private LDS 3 bufs x 4 KB x 4 waves = 48 KB.
// No main-loop barriers; epilogue = 2 sequential combines (4 barriers total).
__global__ __launch_bounds__(256, 4) void proj_kernel(
    const float* __restrict__ x, const float* __restrict__ y, const float* __restrict__ z,
    const float* __restrict__ bq, const float* __restrict__ bk, const float* __restrict__ bv,
    const unsigned short* __restrict__ Wt, unsigned short* __restrict__ qkv)
{
    __shared__ float pool[12288];   // 48 KB: 4 waves x 3 bufs x 1024 f32

    const int bid = (int)blockIdx.x;
    const int mat = bid >> 8;                 // 0=q,1=k,2=v (256 blocks each)
    const int rb  = (bid & 255) * 32;

    const int tid  = (int)threadIdx.x;
    const int lane = tid & 63;
    const int kq   = tid >> 6;                // K-quarter 0..3
    const int c    = lane & 15;
    const int qq   = lane >> 4;

    const float* X  = (mat == 0) ? x  : (mat == 1) ? y  : z;
    const float* Bv = (mat == 0) ? bq : (mat == 1) ? bk : bv;
    const unsigned short* Wm = Wt + (size_t)mat * 65536;
    unsigned short* outp = qkv + (size_t)mat * (SEQ * DIM);

    float* poolw = pool + kq * 3072;
    const float* Xw = X + (size_t)rb * EMB + kq * 256;

    f32x4 acc[2][4];
    #pragma unroll
    for (int r2 = 0; r2 < 2; ++r2)
        #pragma unroll
        for (int i = 0; i < 4; ++i) acc[r2][i] = (f32x4){0.f, 0.f, 0.f, 0.f};

    bf16x8 wreg[3][4];

    // window t: 4 X-gloads (2 per row-group; each 1 KB = 8 rows x 128 B,
    // XOR-preswizzled source) + 4 W-frag loads (lane-contiguous)
    #define STAGE(buf, t)                                                       \
        {                                                                       \
            const int k0_ = (t) * 32;                                           \
            _Pragma("unroll")                                                   \
            for (int rg2 = 0; rg2 < 2; ++rg2)                                   \
                _Pragma("unroll")                                               \
                for (int j = 0; j < 2; ++j) {                                   \
                    const int rloc = j * 8 + (lane >> 3);                       \
                    const int g = (lane & 7) ^ (rloc & 7);                      \
                    gload16(Xw + (size_t)(rg2 * 16 + rloc) * EMB + k0_ + g * 4, \
                            poolw + (buf) * 1024 + rg2 * 512 + j * 256);        \
                }                                                               \
        }
    #define WLOAD(slot, t)                                                      \
        {                                                                       \
            const int sg_ = kq * 8 + (t);                                       \
            _Pragma("unroll")                                                   \
            for (int wc2 = 0; wc2 < 4; ++wc2)                                   \
                wreg[slot][wc2] = *(const bf16x8*)(Wm +                         \
                    ((size_t)(sg_ * 4 + wc2) * 64 + lane) * 8);                 \
        }
    #define COMP(bt)                                                            \
        {                                                                       \
            _Pragma("unroll")                                                   \
            for (int rg2 = 0; rg2 < 2; ++rg2) {                                 \
                const float* rowb = poolw + (bt) * 1024 + rg2 * 512 + c * 32;   \
                float4 fa = *(const float4*)(rowb + (((qq * 2)     ^ (c & 7)) << 2)); \
                float4 fb = *(const float4*)(rowb + (((qq * 2 + 1) ^ (c & 7)) << 2)); \
                bf16x8 af = cvt8(fa, fb);                                       \
                _Pragma("unroll")                                               \
                for (int wc2 = 0; wc2 < 4; ++wc2)                               \
                    acc[rg2][wc2] = __builtin_amdgcn_mfma_f32_16x16x32_bf16(    \
                        af, wreg[bt][wc2], acc[rg2][wc2], 0, 0, 0);             \
            }                                                                   \
        }

    // prologue: windows 0,1,2 (FIFO order pinned by memory clobbers)
    STAGE(0, 0); WLOAD(0, 0);
    asm volatile("" ::: "memory");
    STAGE(1, 1); WLOAD(1, 1);
    asm volatile("" ::: "memory");
    STAGE(2, 2); WLOAD(2, 2);

    #pragma unroll
    for (int t = 0; t < 8; ++t) {
        if (t <= 5)      asm volatile("s_waitcnt vmcnt(16)" ::: "memory");
        else if (t == 6) asm volatile("s_waitcnt vmcnt(8)"  ::: "memory");
        else             asm volatile("s_waitcnt vmcnt(0)"  ::: "memory");
        COMP(t % 3);
        if (t < 5) { STAGE(t % 3, t + 3); WLOAD(t % 3, t + 3); }
    }
    #undef STAGE
    #undef WLOAD
    #undef COMP

    // ---- combine K-quarters, one row-group at a time (reuse pool) ----
    float (*part)[16][68] = (float (*)[16][68])pool;   // 4x16x68 = 17 KB
    const int T2 = rb >> 5;

    #pragma unroll
    for (int rg2 = 0; rg2 < 2; ++rg2) {
        __syncthreads();
        #pragma unroll
        for (int wc2 = 0; wc2 < 4; ++wc2)
            #pragma unroll
            for (int i = 0; i < 4; ++i)
                part[kq][qq * 4 + i][wc2 * 16 + c] = acc[rg2][wc2][i];
        __syncthreads();

        const int cb = rg2 * 16;
        if (mat == 0) {                     // q row-major: uint2/thread
            const int row = tid >> 4;
            const int c0  = (tid & 15) * 4;
            float v0 = part[0][row][c0+0] + part[1][row][c0+0] + part[2][row][c0+0] + part[3][row][c0+0] + Bv[c0+0];
            float v1 = part[0][row][c0+1] + part[1][row][c0+1] + part[2][row][c0+1] + part[3][row][c0+1] + Bv[c0+1];
            float v2 = part[0][row][c0+2] + part[1][row][c0+2] + part[2][row][c0+2] + part[3][row][c0+2] + Bv[c0+2];
            float v3 = part[0][row][c0+3] + part[1][row][c0+3] + part[2][row][c0+3] + part[3][row][c0+3] + Bv[c0+3];
            uint2 pk;
            pk.x = cvtpk(v0, v1); pk.y = cvtpk(v2, v3);
            *(uint2*)&outp[(size_t)(rb + cb + row) * DIM + c0] = pk;
        } else if (mat == 1) {              // KF: ((T2*4+ks)*2+hi)*256 + col*8 + j
            const int jh  = tid & 1;
            const int cl  = (tid >> 1) & 15;
            const int hi2 = (tid >> 5) & 1;
            const int ksf = tid >> 6;
            const int d0  = ksf * 16 + hi2 * 8 + jh * 4;
            float v0 = part[0][cl][d0+0] + part[1][cl][d0+0] + part[2][cl][d0+0] + part[3][cl][d0+0] + Bv[d0+0];
            float v1 = part[0][cl][d0+1] + part[1][cl][d0+1] + part[2][cl][d0+1] + part[3][cl][d0+1] + Bv[d0+1];
            float v2 = part[0][cl][d0+2] + part[1][cl][d0+2] + part[2][cl][d0+2] + part[3][cl][d0+2] + Bv[d0+2];
            float v3 = part[0][cl][d0+3] + part[1][cl][d0+3] + part[2][cl][d0+3] + part[3][cl][d0+3] + Bv[d0+3];
            const size_t base = ((size_t)(T2 * 4 + ksf) * 2 + hi2) * 256 + (size_t)(cb + cl) * 8 + jh * 4;
            uint2 pk;
            pk.x = cvtpk(v0, v1); pk.y = cvtpk(v2, v3);
            *(uint2*)&outp[base] = pk;
        } else {                            // VF: ((T2*2+i)*2+h)*512 + (hi*32+col)*8 + j
            const int jh  = tid & 1;
            const int col = (tid >> 1) & 31;
            const int hi2 = (tid >> 6) & 1;
            const int h   = tid >> 7;
            const int i2  = rg2;
            const int cv  = h * 32 + col;
            const float bb = Bv[cv];
            const int r0 = hi2 * 8 + jh * 4;
            float v0 = part[0][r0+0][cv] + part[1][r0+0][cv] + part[2][r0+0][cv] + part[3][r0+0][cv] + bb;
            float v1 = part[0][r0+1][cv] + part[1][r0+1][cv] + part[2][r0+1][cv] + part[3][r0+1][cv] + bb;
            float v2 = part[0][r0+2][cv] + part[1][r0+2][cv] + part[2][r0+2][cv] + part[3][r0+2][cv] + bb;
            float v3 = part[0][r0+3][cv] + part[1][r0+3][cv] + part[2][r0+3][cv] + part[3][r0+3][cv] + bb;
            const size_t base = ((size_t)(T2 * 2 + i2) * 2 + h) * 512 + (size_t)(hi2 * 32 + col) * 8 + jh * 4;
            uint2 pk;
            pk.x = cvtpk(v0, v1); pk.y = cvtpk(v2, v3);
            *(uint2*)&outp[base] = pk;
        }
    }
}

// ---- Flash attention: swapped-operand 32x32, KVBLK=64 pairs, defer-max -----
// 1152 blocks x 256 thr (4 waves). Unit = (qtile, 32-tile KV chunk).
// Software-pipelined: next pair's K prefetched after current QK; V loads
// after QK (wait hides under softmax). launch_bounds (256,3): DO NOT raise
// to 4 (R8: VGPR cap -> spill, FETCH 9.5->68 MB).
__global__ __launch_bounds__(256, 3) void attn_kernel(
    const unsigned short* __restrict__ qkv, float* __restrict__ out,
    float* __restrict__ Opart, float* __restrict__ MLpart)
{
    const unsigned short* Q  = qkv;
    const unsigned short* KF = qkv + SEQ * DIM;
    const unsigned short* VF = qkv + 2 * SEQ * DIM;

    __shared__ float Oall[4][32][68];
    __shared__ float Ml[4][32][2];
    __shared__ float sScl[4][32];
    __shared__ float sM[32];
    __shared__ float sL[32];

    // unit id, longest-first
    const int u = 1151 - (int)blockIdx.x;
    int g;
    if (u < 32) g = 0; else if (u < 96) g = 1; else if (u < 192) g = 2;
    else if (u < 320) g = 3; else if (u < 480) g = 4; else if (u < 672) g = 5;
    else if (u < 896) g = 6; else g = 7;
    const int o_  = u - 16 * g * (g + 1);
    const int qt  = 32 * g + o_ / (g + 1);
    const int cid = o_ - (o_ / (g + 1)) * (g + 1);

    const int m0 = qt * 32;
    const int tid = (int)threadIdx.x;
    const int lane = tid & 63;
    const int w = tid >> 6;        // 0..3
    const int col = lane & 31;     // q row within tile
    const int hi = lane >> 5;

    bf16x8 qf[4];
    {
        const unsigned short* Qr = Q + (size_t)(m0 + col) * DIM + hi * 8;
        #pragma unroll
        for (int ks = 0; ks < 4; ++ks) qf[ks] = *(const bf16x8*)(Qr + ks * 16);
    }

    f32x16 o0, o1;
    #pragma unroll
    for (int r = 0; r < 16; ++r) { o0[r] = 0.f; o1[r] = 0.f; }
    float m_i = -1e30f, l_i = 0.f;

    const int nT = qt + 1;
    const int tb = cid * 32;
    const int te = (tb + 32 < nT) ? (tb + 32) : nT;
    const int nC = te - tb;
    const int w0 = tb + ((nC * w) >> 2);
    const int w1 = tb + ((nC * (w + 1)) >> 2);
    const int nW = w1 - w0;
    const int nP = nW >> 1;

    // ---- K prefetch for the first pair ----
    bf16x8 kA[4], kB[4];
    if (nP > 0) {
        const unsigned short* kb0 = KF + (size_t)w0 * 2048 + (size_t)lane * 8;
        #pragma unroll
        for (int ks = 0; ks < 4; ++ks) kA[ks] = *(const bf16x8*)(kb0 + ks * 512);
        #pragma unroll
        for (int ks = 0; ks < 4; ++ks) kB[ks] = *(const bf16x8*)(kb0 + 2048 + ks * 512);
    }

    for (int pi = 0; pi < nP; ++pi) {
        const int t = w0 + 2 * pi;

        // ---- dual QK chains (consume kA/kB) ----
        f32x16 sa, sb;
        #pragma unroll
        for (int r = 0; r < 16; ++r) { sa[r] = 0.f; sb[r] = 0.f; }
        __builtin_amdgcn_s_setprio(1);
        #pragma unroll
        for (int ks = 0; ks < 4; ++ks) {
            sa = __builtin_amdgcn_mfma_f32_32x32x16_bf16(kA[ks], qf[ks], sa, 0, 0, 0);
            sb = __builtin_amdgcn_mfma_f32_32x32x16_bf16(kB[ks], qf[ks], sb, 0, 0, 0);
        }
        __builtin_amdgcn_s_setprio(0);

        // ---- prefetch next pair's K (regs dead after QK) ----
        if (pi + 1 < nP) {
            const unsigned short* kbn = KF + (size_t)(t + 2) * 2048 + (size_t)lane * 8;
            #pragma unroll
            for (int ks = 0; ks < 4; ++ks) kA[ks] = *(const bf16x8*)(kbn + ks * 512);
            #pragma unroll
            for (int ks = 0; ks < 4; ++ks) kB[ks] = *(const bf16x8*)(kbn + 2048 + ks * 512);
        }

        // ---- V loads issued here; wait falls before PV (under softmax) ----
        const unsigned short* vb_ = VF + (size_t)t * 2048 + (size_t)lane * 8;
        bf16x8 va[4], vbf[4];
        #pragma unroll
        for (int i = 0; i < 4; ++i) va[i]  = *(const bf16x8*)(vb_ + i * 1024);
        #pragma unroll
        for (int i = 0; i < 4; ++i) vbf[i] = *(const bf16x8*)(vb_ + 512 + i * 1024);

        float p0[16], p1[16];
        #pragma unroll
        for (int r = 0; r < 16; ++r) { p0[r] = sa[r] * SCL; p1[r] = sb[r] * SCL; }
        if (t + 1 == qt) {   // diagonal can only be the second tile of a pair
            #pragma unroll
            for (int r = 0; r < 16; ++r) {
                const int kvr = (r & 3) + 8 * (r >> 2) + 4 * hi;
                if (kvr > col) p1[r] = -1e30f;
            }
        }
        float tm = fmaxf(p0[0], p1[0]);
        #pragma unroll
        for (int r = 1; r < 16; ++r) tm = fmaxf(tm, fmaxf(p0[r], p1[r]));
        tm = fmaxf(tm, __shfl_xor(tm, 32));
        if (!__all(tm <= m_i + 2.0f)) {
            const float mn = fmaxf(m_i, tm);
            const float alpha = EXP2(m_i - mn);
            m_i = mn;
            l_i *= alpha;
            #pragma unroll
            for (int r = 0; r < 16; ++r) { o0[r] *= alpha; o1[r] *= alpha; }
        }
        float rs = 0.f;
        #pragma unroll
        for (int r = 0; r < 16; ++r) { p0[r] = EXP2(p0[r] - m_i); rs += p0[r]; }
        #pragma unroll
        for (int r = 0; r < 16; ++r) { p1[r] = EXP2(p1[r] - m_i); rs += p1[r]; }
        rs += __shfl_xor(rs, 32);
        l_i += rs;

        unsigned pwA[8], pwB[8];
        #pragma unroll
        for (int i = 0; i < 8; ++i) pwA[i] = cvtpk(p0[2 * i], p0[2 * i + 1]);
        #pragma unroll
        for (int i = 0; i < 8; ++i) pwB[i] = cvtpk(p1[2 * i], p1[2 * i + 1]);
        asm volatile("v_permlane32_swap_b32 %0, %1" : "+v"(pwA[0]), "+v"(pwA[2]));
        asm volatile("v_permlane32_swap_b32 %0, %1" : "+v"(pwA[1]), "+v"(pwA[3]));
        asm volatile("v_permlane32_swap_b32 %0, %1" : "+v"(pwA[4]), "+v"(pwA[6]));
        asm volatile("v_permlane32_swap_b32 %0, %1" : "+v"(pwA[5]), "+v"(pwA[7]));
        asm volatile("v_permlane32_swap_b32 %0, %1" : "+v"(pwB[0]), "+v"(pwB[2]));
        asm volatile("v_permlane32_swap_b32 %0, %1" : "+v"(pwB[1]), "+v"(pwB[3]));
        asm volatile("v_permlane32_swap_b32 %0, %1" : "+v"(pwB[4]), "+v"(pwB[6]));
        asm volatile("v_permlane32_swap_b32 %0, %1" : "+v"(pwB[5]), "+v"(pwB[7]));
        union { unsigned uu[4]; bf16x8 v; } pa0, pa1, pb0, pb1;
        pa0.uu[0] = pwA[0]; pa0.uu[1] = pwA[1]; pa0.uu[2] = pwA[2]; pa0.uu[3] = pwA[3];
        pa1.uu[0] = pwA[4]; pa1.uu[1] = pwA[5]; pa1.uu[2] = pwA[6]; pa1.uu[3] = pwA[7];
        pb0.uu[0] = pwB[0]; pb0.uu[1] = pwB[1]; pb0.uu[2] = pwB[2]; pb0.uu[3] = pwB[3];
        pb1.uu[0] = pwB[4]; pb1.uu[1] = pwB[5]; pb1.uu[2] = pwB[6]; pb1.uu[3] = pwB[7];

        __builtin_amdgcn_s_setprio(1);
        o0 = __builtin_amdgcn_mfma_f32_32x32x16_bf16(va[0],  pa0.v, o0, 0, 0, 0);
        o1 = __builtin_amdgcn_mfma_f32_32x32x16_bf16(vbf[0], pa0.v, o1, 0, 0, 0);
        o0 = __builtin_amdgcn_mfma_f32_32x32x16_bf16(va[1],  pa1.v, o0, 0, 0, 0);
        o1 = __builtin_amdgcn_mfma_f32_32x32x16_bf16(vbf[1], pa1.v, o1, 0, 0, 0);
        o0 = __builtin_amdgcn_mfma_f32_32x32x16_bf16(va[2],  pb0.v, o0, 0, 0, 0);
        o1 = __builtin_amdgcn_mfma_f32_32x32x16_bf16(vbf[2], pb0.v, o1, 0, 0, 0);
        o0 = __builtin_amdgcn_mfma_f32_32x32x16_bf16(va[3],  pb1.v, o0, 0, 0, 0);
        o1 = __builtin_amdgcn_mfma_f32_32x32x16_bf16(vbf[3], pb1.v, o1, 0, 0, 0);
        __builtin_amdgcn_s_setprio(0);
    }

    if (nW & 1) {   // tail single tile
        const int t = w1 - 1;
        const unsigned short* kb = KF + (size_t)t * 2048 + (size_t)lane * 8;
        const unsigned short* vb_ = VF + (size_t)t * 2048 + (size_t)lane * 8;
        bf16x8 kT[4];
        #pragma unroll
        for (int ks = 0; ks < 4; ++ks) kT[ks] = *(const bf16x8*)(kb + ks * 512);
        bf16x8 va0 = *(const bf16x8*)(vb_);
        bf16x8 va1 = *(const bf16x8*)(vb_ + 1024);
        bf16x8 vb0 = *(const bf16x8*)(vb_ + 512);
        bf16x8 vb1 = *(const bf16x8*)(vb_ + 1536);

        f32x16 sa;
        #pragma unroll
        for (int r = 0; r < 16; ++r) sa[r] = 0.f;
        __builtin_amdgcn_s_setprio(1);
        #pragma unroll
        for (int ks = 0; ks < 4; ++ks)
            sa = __builtin_amdgcn_mfma_f32_32x32x16_bf16(kT[ks], qf[ks], sa, 0, 0, 0);
        __builtin_amdgcn_s_setprio(0);

        float p0[16];
        #pragma unroll
        for (int r = 0; r < 16; ++r) p0[r] = sa[r] * SCL;
        if (t == qt) {
            #pragma unroll
            for (int r = 0; r < 16; ++r) {
                const int kvr = (r & 3) + 8 * (r >> 2) + 4 * hi;
                if (kvr > col) p0[r] = -1e30f;
            }
        }
        float tm = p0[0];
        #pragma unroll
        for (int r = 1; r < 16; ++r) tm = fmaxf(tm, p0[r]);
        tm = fmaxf(tm, __shfl_xor(tm, 32));
        if (!__all(tm <= m_i + 2.0f)) {
            const float mn = fmaxf(m_i, tm);
            const float alpha = EXP2(m_i - mn);
            m_i = mn;
            l_i *= alpha;
            #pragma unroll
            for (int r = 0; r < 16; ++r) { o0[r] *= alpha; o1[r] *= alpha; }
        }
        float rs = 0.f;
        #pragma unroll
        for (int r = 0; r < 16; ++r) { p0[r] = EXP2(p0[r] - m_i); rs += p0[r]; }
        rs += __shfl_xor(rs, 32);
        l_i += rs;

        unsigned pwA[8];
        #pragma unroll
        for (int i = 0; i < 8; ++i) pwA[i] = cvtpk(p0[2 * i], p0[2 * i + 1]);
        asm volatile("v_permlane32_swap_b32 %0, %1" : "+v"(pwA[0]), "+v"(pwA[2]));
        asm volatile("v_permlane32_swap_b32 %0, %1" : "+v"(pwA[1]), "+v"(pwA[3]));
        asm volatile("v_permlane32_swap_b32 %0, %1" : "+v"(pwA[4]), "+v"(pwA[6]));
        asm volatile("v_permlane32_swap_b32 %0, %1" : "+v"(pwA[5]), "+v"(pwA[7]));
        union { unsigned uu[4]; bf16x8 v; } pa0, pa1;
        pa0.uu[0] = pwA[0]; pa0.uu[1] = pwA[1]; pa0.uu[2] = pwA[2]; pa0.uu[3] = pwA[3];
        pa1.uu[0] = pwA[4]; pa1.uu[1] = pwA[5]; pa1.uu[2] = pwA[6]; pa1.uu[3] = pwA[7];

        __builtin_amdgcn_s_setprio(1);
        o0 = __builtin_amdgcn_mfma_f32_32x32x16_bf16(va0, pa0.v, o0, 0, 0, 0);
        o1 = __builtin_amdgcn_mfma_f32_32x32x16_bf16(vb0, pa0.v, o1, 0, 0, 0);
        o0 = __builtin_amdgcn_mfma_f32_32x32x16_bf16(va1, pa1.v, o0, 0, 0, 0);
        o1 = __builtin_amdgcn_mfma_f32_32x32x16_bf16(vb1, pa1.v, o1, 0, 0, 0);
        __builtin_amdgcn_s_setprio(0);
    }

    // per-wave partial -> LDS (O^T: lane col = q, regs = d)
    #pragma unroll
    for (int r = 0; r < 16; ++r) {
        const int d = (r & 3) + 8 * (r >> 2) + 4 * hi;
        Oall[w][col][d]      = o0[r];
        Oall[w][col][32 + d] = o1[r];
    }
    if (hi == 0) { Ml[w][col][0] = m_i; Ml[w][col][1] = l_i; }
    __syncthreads();

    // 2-barrier epilogue: tid<32 computes M, scl, L in one pass
    if (tid < 32) {
        float M = Ml[0][tid][0];
        #pragma unroll
        for (int w2 = 1; w2 < 4; ++w2) M = fmaxf(M, Ml[w2][tid][0]);
        float L = 0.f;
        #pragma unroll
        for (int w2 = 0; w2 < 4; ++w2) {
            const float sc = EXP2(Ml[w2][tid][0] - M);
            sScl[w2][tid] = sc;
            L += Ml[w2][tid][1] * sc;
        }
        sM[tid] = M;
        sL[tid] = L;
    }
    __syncthreads();

    const int r = tid >> 3;
    const int c0 = (tid & 7) * 8;
    f32x4 a0 = (f32x4){0.f, 0.f, 0.f, 0.f};
    f32x4 a1 = (f32x4){0.f, 0.f, 0.f, 0.f};
    #pragma unroll
    for (int w2 = 0; w2 < 4; ++w2) {
        const float sc = sScl[w2][r];
        const float* Orow = &Oall[w2][r][c0];
        a0 += (*(const f32x4*)(Orow)) * sc;
        a1 += (*(const f32x4*)(Orow + 4)) * sc;
    }
    if (qt < 32) {   // single chunk: final output
        const float inv = 1.f / sL[r];
        float* op = out + (size_t)(m0 + r) * DIM + c0;
        *(f32x4*)(op)     = a0 * inv;
        *(f32x4*)(op + 4) = a1 * inv;
    } else {         // partial for fixup
        const int pb = 16 * (g - 1) * (g + 2) + (qt - 32 * g) * (g + 1) + cid;
        float* op = Opart + (size_t)pb * 2048 + r * 64 + c0;
        *(f32x4*)(op)     = a0;
        *(f32x4*)(op + 4) = a1;
        if (tid < 32) {
            MLpart[(size_t)pb * 64 + tid * 2]     = sM[tid];
            MLpart[(size_t)pb * 64 + tid * 2 + 1] = sL[tid];
        }
    }
}

// ---- Fixup: merge chunk partials for qt >= 32. 224 blocks x 256 ------------
__global__ __launch_bounds__(256) void fixup_kernel(
    const float* __restrict__ Opart, const float* __restrict__ MLpart,
    float* __restrict__ out)
{
    __shared__ float sScl[8][32];
    __shared__ float sInvL[32];

    const int qt = 32 + (int)blockIdx.x;
    const int g  = qt >> 5;
    const int nc = g + 1;
    const int pb = 16 * (g - 1) * (g + 2) + (qt - 32 * g) * nc;
    const int tid = (int)threadIdx.x;

    if (tid < 32) {
        float M = -1e30f;
        for (int c2 = 0; c2 < nc; ++c2)
            M = fmaxf(M, MLpart[(size_t)(pb + c2) * 64 + tid * 2]);
        float L = 0.f;
        for (int c2 = 0; c2 < nc; ++c2) {
            const float sc = EXP2(MLpart[(size_t)(pb + c2) * 64 + tid * 2] - M);
            sScl[c2][tid] = sc;
            L += MLpart[(size_t)(pb + c2) * 64 + tid * 2 + 1] * sc;
        }
        sInvL[tid] = 1.f / L;
    }
    __syncthreads();

    const int r = tid >> 3;
    const int c0 = (tid & 7) * 8;
    f32x4 a0 = (f32x4){0.f, 0.f, 0.f, 0.f};
    f32x4 a1 = (f32x4){0.f, 0.f, 0.f, 0.f};
    for (int c2 = 0; c2 < nc; ++c2) {
        const float sc = sScl[c2][r];
        const float* Op = Opart + (size_t)(pb + c2) * 2048 + r * 64 + c0;
        a0 += (*(const f32x4*)(Op)) * sc;
        a1 += (*(const f32x4*)(Op + 4)) * sc;
    }
    const float inv = sInvL[r];
    float* op = out + (size_t)(qt * 32 + r) * DIM + c0;
    *(f32x4*)(op)     = a0 * inv;
    *(f32x4*)(op + 4) = a1 * inv;
}

extern "C" void kernel_launch(void* const* d_in, const int* in_sizes, int n_in,
                              void* d_out, int out_size, void* d_ws, size_t ws_size,
                              hipStream_t stream) {
    const float* x  = (const float*)d_in[0];
    const float* y  = (const float*)d_in[1];
    const float* z  = (const float*)d_in[2];
    const float* Wq = (const float*)d_in[3];
    const float* bq = (const float*)d_in[4];
    const float* Wk = (const float*)d_in[5];
    const float* bk = (const float*)d_in[6];
    const float* Wv = (const float*)d_in[7];
    const float* bv = (const float*)d_in[8];

    unsigned short* qkv = (unsigned short*)d_ws;
    unsigned short* Wt  = (unsigned short*)((char*)d_ws + 3145728);
    float* Opart        = (float*)((char*)d_ws + 3538944);
    float* MLpart       = (float*)((char*)d_ws + 12713984);
    float* out          = (float*)d_out;

    hipLaunchKernelGGL(wt_kernel,    dim3(48),   dim3(256), 0, stream, Wq, Wk, Wv, Wt);
    hipLaunchKernelGGL(proj_kernel,  dim3(768),  dim3(256), 0, stream, x, y, z, bq, bk, bv, Wt, qkv);
    hipLaunchKernelGGL(attn_kernel,  dim3(1152), dim3(256), 0, stream, qkv, out, Opart, MLpart);
    hipLaunchKernelGGL(fixup_kernel, dim3(224),  dim3(256), 0, stream, Opart, MLpart, out);
}